// Round 3
// baseline (7482.927 us; speedup 1.0000x reference)
//
#include <hip/hip_runtime.h>

// ALIGNN forward on MI355X. Round 2: dtype-self-detecting (f32 or bf16
// inputs), canonicalize to bf16 working copies, NaN-stage telemetry.
// Pipeline: CSR segment aggregation + dst-chunked line-graph m.

typedef unsigned short bfu;
typedef __attribute__((ext_vector_type(8))) short short8;   // 8 bf16 = 4 VGPR
typedef __attribute__((ext_vector_type(4))) float floatx4;  // MFMA C/D

#define CHN 4096        // dst nodes per line-graph chunk (12 chunks)
#define CHCAP 32768     // triplet-row capacity per chunk (mean 21845)

__device__ __forceinline__ float bf2f(bfu u) {
  union { unsigned u; float f; } x; x.u = ((unsigned)u) << 16; return x.f;
}
__device__ __forceinline__ bfu f2bf(float f) {
  union { float f; unsigned u; } x; x.f = f;
  unsigned r = x.u + 0x7FFFu + ((x.u >> 16) & 1u);  // RNE
  return (bfu)(r >> 16);
}

__device__ __forceinline__ float block_sum256(float t, float* sm) {
#pragma unroll
  for (int o = 32; o; o >>= 1) t += __shfl_down(t, o);
  if ((threadIdx.x & 63) == 0) sm[threadIdx.x >> 6] = t;
  __syncthreads();
  float r = sm[0] + sm[1] + sm[2] + sm[3];
  __syncthreads();
  return r;
}

// ------------------------------------------------------- dtype handling ----
// atom_ln_s is all-ones: first 32-bit word is 0x3F800000 iff f32 input.
__global__ void probe_kernel(const unsigned* __restrict__ ones_raw, int* __restrict__ mode) {
  if (threadIdx.x == 0) *mode = (ones_raw[0] == 0x3F800000u) ? 1 : 0;
}

// convert src (f32 or bf16 per *mode) -> bf16
__global__ __launch_bounds__(256) void cvt_kernel(
    const void* __restrict__ src, bfu* __restrict__ dst, int n, const int* __restrict__ mode) {
  int i = blockIdx.x * 256 + threadIdx.x;
  if (i >= n) return;
  dst[i] = (*mode) ? f2bf(((const float*)src)[i]) : ((const bfu*)src)[i];
}

// convert src -> f32
__global__ __launch_bounds__(256) void cvtf_kernel(
    const void* __restrict__ src, float* __restrict__ dst, int n, const int* __restrict__ mode) {
  int i = blockIdx.x * 256 + threadIdx.x;
  if (i >= n) return;
  dst[i] = (*mode) ? ((const float*)src)[i] : bf2f(((const bfu*)src)[i]);
}

// sampled non-finite scan; records FIRST failing stage id
__global__ __launch_bounds__(256) void nanscan_kernel(
    const bfu* __restrict__ buf, long n, int stage, int* __restrict__ ns) {
  long i = ((long)blockIdx.x * 256 + threadIdx.x) * 64;
  if (i >= n) return;
  float v = bf2f(buf[i]);
  if (!isfinite(v)) atomicCAS(ns, 0, stage);
}

// ---------------------------------------------------------------- GEMM ----
// C[rows,N] = A[rows,K] @ W[K,N] + bias (+ G0[gi0[id]] + G1[gi1[id]]).
// Bt = W^T [N,K]. If coff: rows=coff[cn1]-coff[cn0], A row r -> cids[coff[cn0]+r].
template<int BM, int BN, int WR, int WC>
__global__ __launch_bounds__(256) void gemm_kernel(
    const bfu* __restrict__ A, const bfu* __restrict__ Bt,
    const bfu* __restrict__ bias, bfu* __restrict__ Cout,
    int M, int N, int K,
    const int* __restrict__ gi0, const int* __restrict__ gi1,
    const bfu* __restrict__ G0, const bfu* __restrict__ G1,
    const int* __restrict__ coff, int cn0, int cn1, const int* __restrict__ cids)
{
  constexpr int WM = BM / WR, WN = BN / WC;
  constexpr int TM = WM / 16, TN = WN / 16;
  constexpr int LDT = 40;  // 32 + 8 pad (80B row stride)
  __shared__ bfu As[BM * LDT];
  __shared__ bfu Bs[BN * LDT];

  const int tid = threadIdx.x, wave = tid >> 6, lane = tid & 63;
  const int wr = wave / WC, wc = wave % WC;
  const int m0 = blockIdx.x * BM, n0 = blockIdx.y * BN;
  int base = 0, cnt = M;
  if (coff) { base = coff[cn0]; cnt = coff[cn1] - base; }
  if (m0 >= cnt) return;
  const int lrow = lane & 15, kq = (lane >> 4) * 8;

  floatx4 acc[TM][TN];
#pragma unroll
  for (int i = 0; i < TM; ++i)
#pragma unroll
    for (int j = 0; j < TN; ++j) acc[i][j] = (floatx4){0.f, 0.f, 0.f, 0.f};

  constexpr int ACH = BM * 4, BCH = BN * 4;
  for (int k0 = 0; k0 < K; k0 += 32) {
#pragma unroll
    for (int idx = tid; idx < ACH; idx += 256) {
      int row = idx >> 2, kc = (idx & 3) << 3;
      int r = m0 + row, ar = r;
      if (coff) ar = cids[base + (r < cnt ? r : cnt - 1)];
      short8 v = *(const short8*)(const void*)(A + (size_t)ar * K + k0 + kc);
      *(short8*)(void*)(As + row * LDT + kc) = v;
    }
#pragma unroll
    for (int idx = tid; idx < BCH; idx += 256) {
      int row = idx >> 2, kc = (idx & 3) << 3;
      short8 v = *(const short8*)(const void*)(Bt + (size_t)(n0 + row) * K + k0 + kc);
      *(short8*)(void*)(Bs + row * LDT + kc) = v;
    }
    __syncthreads();
    short8 Af[TM], Bf[TN];
#pragma unroll
    for (int i = 0; i < TM; ++i)
      Af[i] = *(const short8*)(const void*)(As + (wr * WM + i * 16 + lrow) * LDT + kq);
#pragma unroll
    for (int j = 0; j < TN; ++j)
      Bf[j] = *(const short8*)(const void*)(Bs + (wc * WN + j * 16 + lrow) * LDT + kq);
#pragma unroll
    for (int i = 0; i < TM; ++i)
#pragma unroll
      for (int j = 0; j < TN; ++j)
        acc[i][j] = __builtin_amdgcn_mfma_f32_16x16x32_bf16(Af[i], Bf[j], acc[i][j], 0, 0, 0);
    __syncthreads();
  }

  const int rquad = lane >> 4, cin = lane & 15;  // D: row=(lane>>4)*4+reg, col=lane&15
#pragma unroll
  for (int i = 0; i < TM; ++i) {
#pragma unroll
    for (int rr = 0; rr < 4; ++rr) {
      int orow = m0 + wr * WM + i * 16 + rquad * 4 + rr;
      if (orow >= cnt) continue;
      int id = coff ? cids[base + orow] : orow;
      int s0 = 0, s1 = 0;
      if (gi0) { s0 = gi0[id]; s1 = gi1[id]; }
#pragma unroll
      for (int j = 0; j < TN; ++j) {
        int gcol = n0 + wc * WN + j * 16 + cin;
        float v = acc[i][j][rr] + bf2f(bias[gcol]);
        if (gi0) v += bf2f(G0[(size_t)s0 * N + gcol]) + bf2f(G1[(size_t)s1 * N + gcol]);
        Cout[(size_t)orow * N + gcol] = f2bf(v);
      }
    }
  }
}

// ----------------------------------------------------------- CSR build ----
__global__ __launch_bounds__(256) void count_kernel(
    const int* __restrict__ d, int* __restrict__ cnt, int ne) {
  int i = blockIdx.x * 256 + threadIdx.x;
  if (i < ne) atomicAdd(&cnt[d[i]], 1);
}

__global__ __launch_bounds__(256) void scan_kernel(
    const int* __restrict__ cnt, int* __restrict__ off, int n) {
  __shared__ int ssum[256];
  __shared__ int sbase[257];
  int t = threadIdx.x;
  int strip = (n + 255) / 256;
  int lo = t * strip, hi = lo + strip; if (hi > n) hi = n; if (lo > n) lo = n;
  int s = 0;
  for (int i = lo; i < hi; ++i) s += cnt[i];
  ssum[t] = s;
  __syncthreads();
  if (t == 0) {
    int run = 0;
    for (int i = 0; i < 256; ++i) { sbase[i] = run; run += ssum[i]; }
    sbase[256] = run;
  }
  __syncthreads();
  int run = sbase[t];
  for (int i = lo; i < hi; ++i) { off[i] = run; run += cnt[i]; }
  if (t == 0) off[n] = sbase[256];
}

__global__ __launch_bounds__(256) void copy_kernel(
    const int* __restrict__ a, int* __restrict__ b, int n) {
  int i = blockIdx.x * 256 + threadIdx.x;
  if (i < n) b[i] = a[i];
}

__global__ __launch_bounds__(256) void fill_kernel(
    const int* __restrict__ d, int* __restrict__ cur, int* __restrict__ ids, int ne) {
  int i = blockIdx.x * 256 + threadIdx.x;
  if (i < ne) ids[atomicAdd(&cur[d[i]], 1)] = i;
}

// ------------------------------------------------------ weight transpose ----
// W [K,N] (f32 or bf16 per *mode) -> Wt [N,Kp] bf16, zero-pad k>=K.
__global__ __launch_bounds__(256) void transpose_pad_kernel(
    const void* __restrict__ W, bfu* __restrict__ Wt, int K, int N, int Kp,
    const int* __restrict__ mode)
{
  size_t bin = (size_t)blockIdx.y * K * N;
  size_t bout = (size_t)blockIdx.y * N * Kp;
  int idx = blockIdx.x * 256 + threadIdx.x;
  if (idx >= N * Kp) return;
  int n = idx / Kp, k = idx - n * Kp;
  bfu v = 0;
  if (k < K) {
    size_t si = bin + (size_t)k * N + n;
    v = (*mode) ? f2bf(((const float*)W)[si]) : ((const bfu*)W)[si];
  }
  Wt[bout + idx] = v;
}

// ----------------------------------------------------------------- RBFs ----
__global__ __launch_bounds__(256) void rbf_triplet_kernel(
    const float* __restrict__ r, const int* __restrict__ lsrc,
    const int* __restrict__ ldst, bfu* __restrict__ out, int T)
{
  int idx = blockIdx.x * 256 + threadIdx.x;
  int t = idx >> 6, j = idx & 63;
  if (t >= T) return;
  int e1 = lsrc[t], e2 = ldst[t];
  float ax = -r[e1 * 3 + 0], ay = -r[e1 * 3 + 1], az = -r[e1 * 3 + 2];
  float bx =  r[e2 * 3 + 0], by =  r[e2 * 3 + 1], bz =  r[e2 * 3 + 2];
  float dot = ax * bx + ay * by + az * bz;
  float na = sqrtf(ax * ax + ay * ay + az * az);
  float nb = sqrtf(bx * bx + by * by + bz * bz);
  float c = dot / (na * nb);
  c = fminf(1.f, fmaxf(-1.f, c));
  float v = 0.f;
  if (j < 40) {
    float center = -1.f + j * (2.f / 39.f);
    float d = c - center;
    v = expf(-19.5f * d * d);
  }
  out[(size_t)t * 64 + j] = f2bf(v);
}

__global__ __launch_bounds__(256) void rbf_edge_kernel(
    const float* __restrict__ r, bfu* __restrict__ out, int E)
{
  int idx = blockIdx.x * 256 + threadIdx.x;
  if (idx >= E * 96) return;
  int e = idx / 96, j = idx - e * 96;
  float x = r[e * 3 + 0], y = r[e * 3 + 1], z = r[e * 3 + 2];
  float bl = sqrtf(x * x + y * y + z * z);
  float v = 0.f;
  if (j < 80) {
    float center = j * (8.f / 79.f);
    float d = bl - center;
    v = expf(-9.875f * d * d);
  }
  out[idx] = f2bf(v);
}

// --------------------------------------------------------- LN + SiLU ops ----
__global__ __launch_bounds__(256) void ln_silu256_kernel(
    const bfu* __restrict__ in, bfu* out,
    const bfu* __restrict__ s, const bfu* __restrict__ b, int residual)
{
  __shared__ float sm[4];
  int row = blockIdx.x, c = threadIdx.x;
  size_t i = (size_t)row * 256 + c;
  float v = bf2f(in[i]);
  float mean = block_sum256(v, sm) * (1.f / 256.f);
  float d = v - mean;
  float var = block_sum256(d * d, sm) * (1.f / 256.f);
  float u = d * rsqrtf(var + 1e-5f) * bf2f(s[c]) + bf2f(b[c]);
  float sil = u / (1.f + expf(-u));
  float res = residual ? bf2f(out[i]) : 0.f;
  out[i] = f2bf(res + sil);
}

__global__ __launch_bounds__(256) void ln_silu64_kernel(
    bfu* __restrict__ buf, const bfu* __restrict__ s, const bfu* __restrict__ b)
{
  int row = blockIdx.x * 4 + (threadIdx.x >> 6);
  int lane = threadIdx.x & 63;
  size_t i = (size_t)row * 64 + lane;
  float v = bf2f(buf[i]);
  float t = v;
#pragma unroll
  for (int o = 32; o; o >>= 1) t += __shfl_down(t, o);
  float mean = __shfl(t, 0) * (1.f / 64.f);
  float d = v - mean;
  t = d * d;
#pragma unroll
  for (int o = 32; o; o >>= 1) t += __shfl_down(t, o);
  float var = __shfl(t, 0) * (1.f / 64.f);
  float u = d * rsqrtf(var + 1e-5f) * bf2f(s[lane]) + bf2f(b[lane]);
  buf[i] = f2bf(u / (1.f + expf(-u)));
}

// edge update for a line-graph chunk: z[id] += silu(ln(mchunk[row]))
__global__ __launch_bounds__(256) void edge_chunk_kernel(
    const bfu* __restrict__ mchunk, bfu* __restrict__ Z,
    const int* __restrict__ coff, int cn0, int cn1, const int* __restrict__ cids,
    const bfu* __restrict__ s, const bfu* __restrict__ b)
{
  __shared__ float sm[4];
  int base = coff[cn0], cnt = coff[cn1] - base;
  int row = blockIdx.x;
  if (row >= cnt) return;
  int t = cids[base + row], c = threadIdx.x;
  float v = bf2f(mchunk[(size_t)row * 256 + c]);
  float mean = block_sum256(v, sm) * (1.f / 256.f);
  float d = v - mean;
  float var = block_sum256(d * d, sm) * (1.f / 256.f);
  float u = d * rsqrtf(var + 1e-5f) * bf2f(s[c]) + bf2f(b[c]);
  float sil = u / (1.f + expf(-u));
  size_t zi = (size_t)t * 256 + c;
  Z[zi] = f2bf(bf2f(Z[zi]) + sil);
}

// fused aggregate + node update
__global__ __launch_bounds__(256) void agg_node_kernel(
    const bfu* __restrict__ mrows, const bfu* __restrict__ u4g,
    const int* __restrict__ esrc, bfu* __restrict__ X, const bfu* __restrict__ u3g,
    const int* __restrict__ coff, const int* __restrict__ cids,
    int node0, int chunk_local,
    const bfu* __restrict__ lns, const bfu* __restrict__ lnb)
{
  __shared__ float sm[4];
  int n = node0 + blockIdx.x, c = threadIdx.x;
  int p0 = coff[n], p1 = coff[n + 1];
  int base = chunk_local ? coff[node0] : 0;
  float num = 0.f, den = 0.f;
  for (int p = p0; p < p1; ++p) {
    int id = cids[p];
    int mrow = chunk_local ? (p - base) : id;
    float sig = 1.f / (1.f + expf(-bf2f(mrows[(size_t)mrow * 256 + c])));
    int sidx = esrc[id];
    num += sig * bf2f(u4g[(size_t)sidx * 256 + c]);
    den += sig;
  }
  int u3row = chunk_local ? (n - node0) : n;
  float pre = bf2f(u3g[(size_t)u3row * 256 + c]) + num / (den + 1e-6f);
  float mean = block_sum256(pre, sm) * (1.f / 256.f);
  float d = pre - mean;
  float var = block_sum256(d * d, sm) * (1.f / 256.f);
  float u = d * rsqrtf(var + 1e-5f) * bf2f(lns[c]) + bf2f(lnb[c]);
  float sil = u / (1.f + expf(-u));
  size_t xi = (size_t)n * 256 + c;
  X[xi] = f2bf(bf2f(X[xi]) + sil);
}

// ----------------------------------------------------------- atom init ----
__global__ __launch_bounds__(256) void atom_init_kernel(
    const bfu* __restrict__ af, const bfu* __restrict__ W, const bfu* __restrict__ bias,
    const bfu* __restrict__ lns, const bfu* __restrict__ lnb, bfu* __restrict__ X)
{
  __shared__ float sm[4];
  int row = blockIdx.x, c = threadIdx.x;
  float acc = bf2f(bias[c]);
  for (int k = 0; k < 92; ++k)
    acc += bf2f(af[row * 92 + k]) * bf2f(W[k * 256 + c]);
  float mean = block_sum256(acc, sm) * (1.f / 256.f);
  float d = acc - mean;
  float var = block_sum256(d * d, sm) * (1.f / 256.f);
  float u = d * rsqrtf(var + 1e-5f) * bf2f(lns[c]) + bf2f(lnb[c]);
  X[(size_t)row * 256 + c] = f2bf(u / (1.f + expf(-u)));
}

// --------------------------------------------------------------- final ----
__global__ __launch_bounds__(256) void final_kernel(
    const bfu* __restrict__ X, const bfu* __restrict__ fcW, const bfu* __restrict__ fcb,
    void* __restrict__ out, float* __restrict__ acc, const int* __restrict__ mode)
{
  int row = blockIdx.x * 4 + (threadIdx.x >> 6);
  int lane = threadIdx.x & 63;
  float s = 0.f;
#pragma unroll
  for (int k = 0; k < 4; ++k)
    s += bf2f(X[(size_t)row * 256 + lane + k * 64]) * bf2f(fcW[lane + k * 64]);
#pragma unroll
  for (int o = 32; o; o >>= 1) s += __shfl_down(s, o);
  if (lane == 0) {
    float v = s + bf2f(fcb[0]);
    if (*mode) ((float*)out)[1 + row] = v;
    else       ((bfu*)out)[1 + row] = f2bf(v);
    atomicAdd(acc, v);
  }
}

__global__ void mean_kernel(const float* __restrict__ acc, void* __restrict__ out,
                            const int* __restrict__ mode, const int* __restrict__ ns) {
  if (threadIdx.x == 0) {
    float v = acc[0] * (1.f / 4096.f);
    int s = *ns;
    if (s) v = 1000.f + (float)s;  // telemetry: first non-finite stage
    if (*mode) ((float*)out)[0] = v;
    else       ((bfu*)out)[0] = f2bf(v);
  }
}

__global__ void dbg_kernel(void* __restrict__ out, float v) {
  if (threadIdx.x == 0) { ((bfu*)out)[0] = f2bf(v); ((float*)out)[1] = v; }
}

// ---------------------------------------------------------------- host ----
static void gemm(const bfu* A, const bfu* Bt, const bfu* bias, bfu* C,
                 int M, int N, int K,
                 const int* gi0, const int* gi1, const bfu* G0, const bfu* G1,
                 const int* coff, int cn0, int cn1, const int* cids,
                 hipStream_t st) {
  if (N % 128 == 0) {
    dim3 g(M / 128, N / 128);
    gemm_kernel<128, 128, 2, 2><<<g, 256, 0, st>>>(A, Bt, bias, C, M, N, K,
        gi0, gi1, G0, G1, coff, cn0, cn1, cids);
  } else {
    dim3 g(M / 128, N / 64);
    gemm_kernel<128, 64, 4, 1><<<g, 256, 0, st>>>(A, Bt, bias, C, M, N, K,
        gi0, gi1, G0, G1, coff, cn0, cn1, cids);
  }
}

extern "C" void kernel_launch(void* const* d_in, const int* in_sizes, int n_in,
                              void* d_out, int out_size, void* d_ws, size_t ws_size,
                              hipStream_t stream) {
  const int N = 4096, E = 49152, T = 262144, H = 256;

  const int* src  = (const int*)d_in[2];
  const int* dst  = (const int*)d_in[3];
  const int* lsrc = (const int*)d_in[4];
  const int* ldst = (const int*)d_in[5];

  // ---- workspace carve ----
  char* bp = (char*)d_ws;
  size_t off = 0;
  auto carve = [&](size_t bytes) -> char* {
    char* q = bp + off;
    off = (off + bytes + 255) & ~(size_t)255;
    return q;
  };
  bfu* x       = (bfu*)carve((size_t)N * H * 2);
  bfu* y       = (bfu*)carve((size_t)E * H * 2);
  bfu* z       = (bfu*)carve((size_t)T * H * 2);
  bfu* reg     = (bfu*)carve((size_t)3 * E * H * 2);
  bfu* u3c     = (bfu*)carve((size_t)CHN * H * 2);
  bfu* mchunk  = (bfu*)carve((size_t)CHCAP * H * 2);
  bfu* WtE     = (bfu*)carve((size_t)60 * H * H * 2);
  bfu* Wt_a1   = (bfu*)carve(64 * 64 * 2);
  bfu* Wt_a2   = (bfu*)carve(256 * 64 * 2);
  bfu* Wt_e1   = (bfu*)carve(64 * 96 * 2);
  bfu* Wt_e2   = (bfu*)carve(256 * 64 * 2);
  int* aoff    = (int*)carve((size_t)(N + 1) * 4);
  int* aids    = (int*)carve((size_t)E * 4);
  int* loff    = (int*)carve((size_t)(E + 1) * 4);
  int* lids    = (int*)carve((size_t)T * 4);
  int* cursors = (int*)carve((size_t)E * 4);
  float* macc  = (float*)carve(256);
  int* mode    = (int*)carve(256);
  int* nstage  = (int*)carve(256);
  // canonical bf16 copies of float inputs
  bfu* af_c    = (bfu*)carve((size_t)N * 92 * 2);
  float* r_f   = (float*)carve((size_t)E * 3 * 4);
  bfu* atW_c   = (bfu*)carve(92 * 256 * 2);
  bfu* par_c   = (bfu*)carve(65536 * 2);   // packed small params

  if (off > ws_size) {
    hipMemsetAsync(d_out, 0, (size_t)out_size * 2, stream);
    dbg_kernel<<<1, 64, 0, stream>>>(d_out, (float)(ws_size >> 20));
    return;
  }

  // packed param layout inside par_c
  bfu* atom_b_c   = par_c + 0;
  bfu* atom_lns_c = par_c + 256;
  bfu* atom_lnb_c = par_c + 512;
  bfu* e_b1_c     = par_c + 768;
  bfu* e_l1s_c    = par_c + 832;
  bfu* e_l1b_c    = par_c + 896;
  bfu* e_b2_c     = par_c + 1024;
  bfu* e_l2s_c    = par_c + 1280;
  bfu* e_l2b_c    = par_c + 1536;
  bfu* a_b1_c     = par_c + 1792;
  bfu* a_l1s_c    = par_c + 1856;
  bfu* a_l1b_c    = par_c + 1920;
  bfu* a_b2_c     = par_c + 2048;
  bfu* a_l2s_c    = par_c + 2304;
  bfu* a_l2b_c    = par_c + 2560;
  bfu* fcW_c      = par_c + 2816;
  bfu* fcb_c      = par_c + 3072;
  bfu* eb_c       = par_c + 3328;            // eggc_b   [12*5*256=15360]
  bfu* els_c      = par_c + 3328 + 15360;    // eggc_ln_s [6144]
  bfu* elb_c      = par_c + 3328 + 21504;    // eggc_ln_b [6144]

  // line-graph scratch views
  bfu* g0 = reg;
  bfu* g1 = reg + (size_t)E * H;
  bfu* u4 = reg + (size_t)2 * E * H;
  // atom-graph views (overlay)
  bfu* g0a   = reg;
  bfu* g1a   = reg + (size_t)1 * N * H;
  bfu* u3a   = reg + (size_t)2 * N * H;
  bfu* u4a   = reg + (size_t)3 * N * H;
  bfu* mbufa = reg + (size_t)4 * N * H;
  // early-phase overlays
  bfu* rbf_t = reg;
  bfu* emb_t = reg + (size_t)T * 64;
  bfu* rbf_e = reg;
  bfu* emb_e = reg + (size_t)E * 96;

  // ---- dtype probe + canonicalize ----
  probe_kernel<<<1, 64, 0, stream>>>((const unsigned*)d_in[8], mode);
  hipMemsetAsync(nstage, 0, 4, stream);
  auto cvt = [&](int idx, bfu* dstp, int n) {
    cvt_kernel<<<(n + 255) / 256, 256, 0, stream>>>(d_in[idx], dstp, n, mode);
  };
  cvt(0, af_c, N * 92);
  cvtf_kernel<<<(E * 3 + 255) / 256, 256, 0, stream>>>(d_in[1], r_f, E * 3, mode);
  cvt(6, atW_c, 92 * 256);
  cvt(7, atom_b_c, 256);  cvt(8, atom_lns_c, 256);  cvt(9, atom_lnb_c, 256);
  cvt(11, e_b1_c, 64);    cvt(12, e_l1s_c, 64);     cvt(13, e_l1b_c, 64);
  cvt(15, e_b2_c, 256);   cvt(16, e_l2s_c, 256);    cvt(17, e_l2b_c, 256);
  cvt(19, a_b1_c, 64);    cvt(20, a_l1s_c, 64);     cvt(21, a_l1b_c, 64);
  cvt(23, a_b2_c, 256);   cvt(24, a_l2s_c, 256);    cvt(25, a_l2b_c, 256);
  cvt(27, eb_c, 12 * 5 * 256);
  cvt(28, els_c, 12 * 2 * 256);
  cvt(29, elb_c, 12 * 2 * 256);
  cvt(30, fcW_c, 256);    cvt(31, fcb_c, 1);

  // ---- CSR builds ----
  hipMemsetAsync(cursors, 0, (size_t)N * 4, stream);
  count_kernel<<<E / 256, 256, 0, stream>>>(dst, cursors, E);
  scan_kernel<<<1, 256, 0, stream>>>(cursors, aoff, N);
  copy_kernel<<<(N + 255) / 256, 256, 0, stream>>>(aoff, cursors, N);
  fill_kernel<<<E / 256, 256, 0, stream>>>(dst, cursors, aids, E);

  hipMemsetAsync(cursors, 0, (size_t)E * 4, stream);
  count_kernel<<<T / 256, 256, 0, stream>>>(ldst, cursors, T);
  scan_kernel<<<1, 256, 0, stream>>>(cursors, loff, E);
  copy_kernel<<<(E + 255) / 256, 256, 0, stream>>>(loff, cursors, E);
  fill_kernel<<<T / 256, 256, 0, stream>>>(ldst, cursors, lids, T);

  // ---- weight transposes (mode-aware) ----
  transpose_pad_kernel<<<dim3(256, 60), 256, 0, stream>>>(d_in[26], WtE, 256, 256, 256, mode);
  transpose_pad_kernel<<<dim3(16, 1), 256, 0, stream>>>(d_in[18], Wt_a1, 40, 64, 64, mode);
  transpose_pad_kernel<<<dim3(64, 1), 256, 0, stream>>>(d_in[22], Wt_a2, 64, 256, 64, mode);
  transpose_pad_kernel<<<dim3(24, 1), 256, 0, stream>>>(d_in[10], Wt_e1, 80, 64, 96, mode);
  transpose_pad_kernel<<<dim3(64, 1), 256, 0, stream>>>(d_in[14], Wt_e2, 64, 256, 64, mode);

  // ---- z = MLP(MLP(rbf(cos))) ----
  rbf_triplet_kernel<<<(T * 64) / 256, 256, 0, stream>>>(r_f, lsrc, ldst, rbf_t, T);
  gemm(rbf_t, Wt_a1, a_b1_c, emb_t, T, 64, 64, 0, 0, 0, 0, 0, 0, 0, 0, stream);
  ln_silu64_kernel<<<T / 4, 256, 0, stream>>>(emb_t, a_l1s_c, a_l1b_c);
  gemm(emb_t, Wt_a2, a_b2_c, z, T, 256, 64, 0, 0, 0, 0, 0, 0, 0, 0, stream);
  ln_silu256_kernel<<<T, 256, 0, stream>>>(z, z, a_l2s_c, a_l2b_c, 0);
  nanscan_kernel<<<(T * 256 / 64 + 255) / 256, 256, 0, stream>>>(z, (long)T * 256, 1, nstage);

  // ---- y = MLP(MLP(rbf(bondlength))) ----
  rbf_edge_kernel<<<(E * 96 + 255) / 256, 256, 0, stream>>>(r_f, rbf_e, E);
  gemm(rbf_e, Wt_e1, e_b1_c, emb_e, E, 64, 96, 0, 0, 0, 0, 0, 0, 0, 0, stream);
  ln_silu64_kernel<<<E / 4, 256, 0, stream>>>(emb_e, e_l1s_c, e_l1b_c);
  gemm(emb_e, Wt_e2, e_b2_c, y, E, 256, 64, 0, 0, 0, 0, 0, 0, 0, 0, stream);
  ln_silu256_kernel<<<E, 256, 0, stream>>>(y, y, e_l2s_c, e_l2b_c, 0);
  nanscan_kernel<<<(E * 256 / 64 + 255) / 256, 256, 0, stream>>>(y, (long)E * 256, 2, nstage);

  // ---- x = MLP(atom_features) ----
  atom_init_kernel<<<N, 256, 0, stream>>>(af_c, atW_c, atom_b_c, atom_lns_c, atom_lnb_c, x);
  nanscan_kernel<<<(N * 256 / 64 + 255) / 256, 256, 0, stream>>>(x, (long)N * 256, 3, nstage);

  // ---- EGGC blocks ----
  auto atom_eggc = [&](int blk, int do_edge) {
    const bfu* W  = WtE + (size_t)blk * 5 * H * H;
    const bfu* bb = eb_c + (size_t)blk * 5 * H;
    const bfu* ls = els_c + (size_t)blk * 2 * H;
    const bfu* lb = elb_c + (size_t)blk * 2 * H;
    gemm(x, W + 0 * H * H, bb + 0 * H, g0a, N, H, H, 0, 0, 0, 0, 0, 0, 0, 0, stream);
    gemm(x, W + 1 * H * H, bb + 1 * H, g1a, N, H, H, 0, 0, 0, 0, 0, 0, 0, 0, stream);
    gemm(x, W + 3 * H * H, bb + 3 * H, u3a, N, H, H, 0, 0, 0, 0, 0, 0, 0, 0, stream);
    gemm(x, W + 4 * H * H, bb + 4 * H, u4a, N, H, H, 0, 0, 0, 0, 0, 0, 0, 0, stream);
    gemm(y, W + 2 * H * H, bb + 2 * H, mbufa, E, H, H, src, dst, g0a, g1a, 0, 0, 0, 0, stream);
    agg_node_kernel<<<N, 256, 0, stream>>>(mbufa, u4a, src, x, u3a, aoff, aids, 0, 0, ls, lb);
    if (do_edge)
      ln_silu256_kernel<<<E, 256, 0, stream>>>(mbufa, y, ls + H, lb + H, 1);
    nanscan_kernel<<<(N * 256 / 64 + 255) / 256, 256, 0, stream>>>(x, (long)N * 256, 10 + blk, nstage);
  };

  auto line_eggc = [&](int blk, int do_edge) {
    const bfu* W  = WtE + (size_t)blk * 5 * H * H;
    const bfu* bb = eb_c + (size_t)blk * 5 * H;
    const bfu* ls = els_c + (size_t)blk * 2 * H;
    const bfu* lb = elb_c + (size_t)blk * 2 * H;
    gemm(y, W + 0 * H * H, bb + 0 * H, g0, E, H, H, 0, 0, 0, 0, 0, 0, 0, 0, stream);
    gemm(y, W + 1 * H * H, bb + 1 * H, g1, E, H, H, 0, 0, 0, 0, 0, 0, 0, 0, stream);
    gemm(y, W + 4 * H * H, bb + 4 * H, u4, E, H, H, 0, 0, 0, 0, 0, 0, 0, 0, stream);
    for (int c = 0; c < E / CHN; ++c) {
      int n0 = c * CHN, n1 = n0 + CHN;
      gemm(y + (size_t)n0 * H, W + 3 * H * H, bb + 3 * H, u3c, CHN, H, H,
           0, 0, 0, 0, 0, 0, 0, 0, stream);
      gemm(z, W + 2 * H * H, bb + 2 * H, mchunk, CHCAP, H, H,
           lsrc, ldst, g0, g1, loff, n0, n1, lids, stream);
      if (do_edge)
        edge_chunk_kernel<<<CHCAP, 256, 0, stream>>>(mchunk, z, loff, n0, n1, lids,
                                                     ls + H, lb + H);
      agg_node_kernel<<<CHN, 256, 0, stream>>>(mchunk, u4, lsrc, y, u3c,
                                               loff, lids, n0, 1, ls, lb);
    }
    nanscan_kernel<<<(E * 256 / 64 + 255) / 256, 256, 0, stream>>>(y, (long)E * 256, 10 + blk, nstage);
  };

  for (int i = 0; i < 4; ++i) {
    atom_eggc(2 * i, 1);
    line_eggc(2 * i + 1, i < 3);   // block 7's z-update is dead
  }
  for (int i = 0; i < 4; ++i)
    atom_eggc(8 + i, i < 3);       // block 11's y-update is dead

  // ---- output ----
  hipMemsetAsync(macc, 0, 4, stream);
  final_kernel<<<N / 4, 256, 0, stream>>>(x, fcW_c, fcb_c, d_out, macc, mode);
  mean_kernel<<<1, 64, 0, stream>>>(macc, d_out, mode, nstage);
}

// Round 4
// 5775.623 us; speedup vs baseline: 1.2956x; 1.2956x over previous
//
#include <hip/hip_runtime.h>

// ALIGNN forward on MI355X. Round 3: permuted-z line graph (contiguous
// m-GEMM), batched gate GEMMs, fused edge+agg kernel.

typedef unsigned short bfu;
typedef __attribute__((ext_vector_type(8))) short short8;   // 8 bf16 = 4 VGPR
typedef __attribute__((ext_vector_type(4))) float floatx4;  // MFMA C/D

#define CHN 4096        // dst nodes per line-graph chunk (12 chunks)
#define CHCAP 24576     // row capacity per chunk (mean 21845, sigma~141 -> +19s)

__device__ __forceinline__ float bf2f(bfu u) {
  union { unsigned u; float f; } x; x.u = ((unsigned)u) << 16; return x.f;
}
__device__ __forceinline__ bfu f2bf(float f) {
  union { float f; unsigned u; } x; x.f = f;
  unsigned r = x.u + 0x7FFFu + ((x.u >> 16) & 1u);  // RNE
  return (bfu)(r >> 16);
}

__device__ __forceinline__ float block_sum256(float t, float* sm) {
#pragma unroll
  for (int o = 32; o; o >>= 1) t += __shfl_down(t, o);
  if ((threadIdx.x & 63) == 0) sm[threadIdx.x >> 6] = t;
  __syncthreads();
  float r = sm[0] + sm[1] + sm[2] + sm[3];
  __syncthreads();
  return r;
}

// ------------------------------------------------------- dtype handling ----
__global__ void probe_kernel(const unsigned* __restrict__ ones_raw, int* __restrict__ mode) {
  if (threadIdx.x == 0) *mode = (ones_raw[0] == 0x3F800000u) ? 1 : 0;
}
__global__ __launch_bounds__(256) void cvt_kernel(
    const void* __restrict__ src, bfu* __restrict__ dst, int n, const int* __restrict__ mode) {
  int i = blockIdx.x * 256 + threadIdx.x;
  if (i >= n) return;
  dst[i] = (*mode) ? f2bf(((const float*)src)[i]) : ((const bfu*)src)[i];
}
__global__ __launch_bounds__(256) void cvtf_kernel(
    const void* __restrict__ src, float* __restrict__ dst, int n, const int* __restrict__ mode) {
  int i = blockIdx.x * 256 + threadIdx.x;
  if (i >= n) return;
  dst[i] = (*mode) ? ((const float*)src)[i] : bf2f(((const bfu*)src)[i]);
}

// ---------------------------------------------------------------- GEMM ----
// C[rows,N] = A[rows,K] @ W[K,N] + bias (+ G0[gi0[p]]·gstride + G1[gi1[p]]).
// Bt = W^T [N,K]. If coff: base=coff[cn0], cnt=coff[cn1]-base; A row r maps
// to global row base+r (contiguous, clamped); epilogue id p = base+orow.
template<int BM, int BN, int WR, int WC>
__global__ __launch_bounds__(256) void gemm_kernel(
    const bfu* __restrict__ A, const bfu* __restrict__ Bt,
    const bfu* __restrict__ bias, bfu* __restrict__ Cout,
    int M, int N, int K,
    const int* __restrict__ gi0, const int* __restrict__ gi1,
    const bfu* __restrict__ G0, const bfu* __restrict__ G1, int gstride,
    const int* __restrict__ coff, int cn0, int cn1)
{
  constexpr int WM = BM / WR, WN = BN / WC;
  constexpr int TM = WM / 16, TN = WN / 16;
  constexpr int LDT = 40;  // 32 + 8 pad
  __shared__ bfu As[BM * LDT];
  __shared__ bfu Bs[BN * LDT];

  const int tid = threadIdx.x, wave = tid >> 6, lane = tid & 63;
  const int wr = wave / WC, wc = wave % WC;
  const int m0 = blockIdx.x * BM, n0 = blockIdx.y * BN;
  int base = 0, cnt = M;
  if (coff) { base = coff[cn0]; cnt = coff[cn1] - base; }
  if (m0 >= cnt) return;
  const int lrow = lane & 15, kq = (lane >> 4) * 8;

  floatx4 acc[TM][TN];
#pragma unroll
  for (int i = 0; i < TM; ++i)
#pragma unroll
    for (int j = 0; j < TN; ++j) acc[i][j] = (floatx4){0.f, 0.f, 0.f, 0.f};

  constexpr int ACH = BM * 4, BCH = BN * 4;
  for (int k0 = 0; k0 < K; k0 += 32) {
#pragma unroll
    for (int idx = tid; idx < ACH; idx += 256) {
      int row = idx >> 2, kc = (idx & 3) << 3;
      int r = m0 + row;
      int ar = base + (r < cnt ? r : cnt - 1);
      short8 v = *(const short8*)(const void*)(A + (size_t)ar * K + k0 + kc);
      *(short8*)(void*)(As + row * LDT + kc) = v;
    }
#pragma unroll
    for (int idx = tid; idx < BCH; idx += 256) {
      int row = idx >> 2, kc = (idx & 3) << 3;
      short8 v = *(const short8*)(const void*)(Bt + (size_t)(n0 + row) * K + k0 + kc);
      *(short8*)(void*)(Bs + row * LDT + kc) = v;
    }
    __syncthreads();
    short8 Af[TM], Bf[TN];
#pragma unroll
    for (int i = 0; i < TM; ++i)
      Af[i] = *(const short8*)(const void*)(As + (wr * WM + i * 16 + lrow) * LDT + kq);
#pragma unroll
    for (int j = 0; j < TN; ++j)
      Bf[j] = *(const short8*)(const void*)(Bs + (wc * WN + j * 16 + lrow) * LDT + kq);
#pragma unroll
    for (int i = 0; i < TM; ++i)
#pragma unroll
      for (int j = 0; j < TN; ++j)
        acc[i][j] = __builtin_amdgcn_mfma_f32_16x16x32_bf16(Af[i], Bf[j], acc[i][j], 0, 0, 0);
    __syncthreads();
  }

  const int rquad = lane >> 4, cin = lane & 15;  // D: row=(lane>>4)*4+reg, col=lane&15
#pragma unroll
  for (int i = 0; i < TM; ++i) {
#pragma unroll
    for (int rr = 0; rr < 4; ++rr) {
      int orow = m0 + wr * WM + i * 16 + rquad * 4 + rr;
      if (orow >= cnt) continue;
      int s0 = 0, s1 = 0;
      if (gi0) { int p = base + orow; s0 = gi0[p]; s1 = gi1[p]; }
#pragma unroll
      for (int j = 0; j < TN; ++j) {
        int gcol = n0 + wc * WN + j * 16 + cin;
        float v = acc[i][j][rr] + bf2f(bias[gcol]);
        if (gi0) v += bf2f(G0[(size_t)s0 * gstride + gcol]) + bf2f(G1[(size_t)s1 * gstride + gcol]);
        Cout[(size_t)orow * N + gcol] = f2bf(v);
      }
    }
  }
}

// ----------------------------------------------------------- CSR build ----
__global__ __launch_bounds__(256) void count_kernel(
    const int* __restrict__ d, int* __restrict__ cnt, int ne) {
  int i = blockIdx.x * 256 + threadIdx.x;
  if (i < ne) atomicAdd(&cnt[d[i]], 1);
}
__global__ __launch_bounds__(256) void scan_kernel(
    const int* __restrict__ cnt, int* __restrict__ off, int n) {
  __shared__ int ssum[256];
  __shared__ int sbase[257];
  int t = threadIdx.x;
  int strip = (n + 255) / 256;
  int lo = t * strip, hi = lo + strip; if (hi > n) hi = n; if (lo > n) lo = n;
  int s = 0;
  for (int i = lo; i < hi; ++i) s += cnt[i];
  ssum[t] = s;
  __syncthreads();
  if (t == 0) {
    int run = 0;
    for (int i = 0; i < 256; ++i) { sbase[i] = run; run += ssum[i]; }
    sbase[256] = run;
  }
  __syncthreads();
  int run = sbase[t];
  for (int i = lo; i < hi; ++i) { off[i] = run; run += cnt[i]; }
  if (t == 0) off[n] = sbase[256];
}
__global__ __launch_bounds__(256) void copy_kernel(
    const int* __restrict__ a, int* __restrict__ b, int n) {
  int i = blockIdx.x * 256 + threadIdx.x;
  if (i < n) b[i] = a[i];
}
__global__ __launch_bounds__(256) void fill_kernel(
    const int* __restrict__ d, int* __restrict__ cur, int* __restrict__ ids, int ne) {
  int i = blockIdx.x * 256 + threadIdx.x;
  if (i < ne) ids[atomicAdd(&cur[d[i]], 1)] = i;
}
// lsrc_p[i] = lsrc[lids[i]], ldst_p[i] = ldst[lids[i]]
__global__ __launch_bounds__(256) void perm_idx_kernel(
    const int* __restrict__ lids, const int* __restrict__ lsrc, const int* __restrict__ ldst,
    int* __restrict__ lsrc_p, int* __restrict__ ldst_p, int n) {
  int i = blockIdx.x * 256 + threadIdx.x;
  if (i >= n) return;
  int id = lids[i];
  lsrc_p[i] = lsrc[id];
  ldst_p[i] = ldst[id];
}

// ------------------------------------------------------ weight transpose ----
__global__ __launch_bounds__(256) void transpose_pad_kernel(
    const void* __restrict__ W, bfu* __restrict__ Wt, int K, int N, int Kp,
    const int* __restrict__ mode)
{
  int idx = blockIdx.x * 256 + threadIdx.x;
  if (idx >= N * Kp) return;
  int n = idx / Kp, k = idx - n * Kp;
  bfu v = 0;
  if (k < K) {
    size_t si = (size_t)k * N + n;
    v = (*mode) ? f2bf(((const float*)W)[si]) : ((const bfu*)W)[si];
  }
  Wt[idx] = v;
}

// eggc weights: [blk][mat][256k][256n] -> Wt [blk][slot][256n][256k]
// slot order: line blocks (odd, <8): W0,W1,W4,W3,W2; atom: W0,W1,W3,W4,W2
__device__ __forceinline__ int slot2mat(int blk, int slot) {
  int is_line = (blk & 1) && (blk < 8);
  if (slot < 2) return slot;
  if (is_line) return slot == 2 ? 4 : (slot == 3 ? 3 : 2);
  return slot == 2 ? 3 : (slot == 3 ? 4 : 2);
}
__global__ __launch_bounds__(256) void transpose_eggc_kernel(
    const void* __restrict__ W, bfu* __restrict__ Wt, const int* __restrict__ mode)
{
  int bs = blockIdx.y;                    // blk*5 + slot
  int blk = bs / 5, slot = bs - blk * 5;
  int mat = slot2mat(blk, slot);
  int idx = blockIdx.x * 256 + threadIdx.x;   // n*256 + k
  int n = idx >> 8, k = idx & 255;
  size_t si = ((size_t)(blk * 5 + mat) * 256 + k) * 256 + n;
  bfu v = (*mode) ? f2bf(((const float*)W)[si]) : ((const bfu*)W)[si];
  Wt[((size_t)bs * 256 + n) * 256 + k] = v;
}
__global__ __launch_bounds__(256) void bias_perm_kernel(
    const void* __restrict__ B, bfu* __restrict__ Bp, const int* __restrict__ mode)
{
  int i = blockIdx.x * 256 + threadIdx.x;   // < 12*5*256
  int bs = i >> 8, c = i & 255;
  int blk = bs / 5, slot = bs - blk * 5;
  int mat = slot2mat(blk, slot);
  size_t si = (size_t)(blk * 5 + mat) * 256 + c;
  Bp[i] = (*mode) ? f2bf(((const float*)B)[si]) : ((const bfu*)B)[si];
}

// ----------------------------------------------------------------- RBFs ----
__global__ __launch_bounds__(256) void rbf_triplet_kernel(
    const float* __restrict__ r, const int* __restrict__ lsrc_p,
    const int* __restrict__ ldst_p, bfu* __restrict__ out, int T)
{
  int idx = blockIdx.x * 256 + threadIdx.x;
  int t = idx >> 6, j = idx & 63;
  if (t >= T) return;
  int e1 = lsrc_p[t], e2 = ldst_p[t];
  float ax = -r[e1 * 3 + 0], ay = -r[e1 * 3 + 1], az = -r[e1 * 3 + 2];
  float bx =  r[e2 * 3 + 0], by =  r[e2 * 3 + 1], bz =  r[e2 * 3 + 2];
  float dot = ax * bx + ay * by + az * bz;
  float na = sqrtf(ax * ax + ay * ay + az * az);
  float nb = sqrtf(bx * bx + by * by + bz * bz);
  float c = dot / (na * nb);
  c = fminf(1.f, fmaxf(-1.f, c));
  float v = 0.f;
  if (j < 40) {
    float center = -1.f + j * (2.f / 39.f);
    float d = c - center;
    v = expf(-19.5f * d * d);
  }
  out[(size_t)t * 64 + j] = f2bf(v);
}
__global__ __launch_bounds__(256) void rbf_edge_kernel(
    const float* __restrict__ r, bfu* __restrict__ out, int E)
{
  int idx = blockIdx.x * 256 + threadIdx.x;
  if (idx >= E * 96) return;
  int e = idx / 96, j = idx - e * 96;
  float x = r[e * 3 + 0], y = r[e * 3 + 1], z = r[e * 3 + 2];
  float bl = sqrtf(x * x + y * y + z * z);
  float v = 0.f;
  if (j < 80) {
    float center = j * (8.f / 79.f);
    float d = bl - center;
    v = expf(-9.875f * d * d);
  }
  out[idx] = f2bf(v);
}

// --------------------------------------------------------- LN + SiLU ops ----
__global__ __launch_bounds__(256) void ln_silu256_kernel(
    const bfu* __restrict__ in, bfu* out,
    const bfu* __restrict__ s, const bfu* __restrict__ b, int residual)
{
  __shared__ float sm[4];
  int row = blockIdx.x, c = threadIdx.x;
  size_t i = (size_t)row * 256 + c;
  float v = bf2f(in[i]);
  float mean = block_sum256(v, sm) * (1.f / 256.f);
  float d = v - mean;
  float var = block_sum256(d * d, sm) * (1.f / 256.f);
  float u = d * rsqrtf(var + 1e-5f) * bf2f(s[c]) + bf2f(b[c]);
  float sil = u / (1.f + expf(-u));
  float res = residual ? bf2f(out[i]) : 0.f;
  out[i] = f2bf(res + sil);
}
__global__ __launch_bounds__(256) void ln_silu64_kernel(
    bfu* __restrict__ buf, const bfu* __restrict__ s, const bfu* __restrict__ b)
{
  int row = blockIdx.x * 4 + (threadIdx.x >> 6);
  int lane = threadIdx.x & 63;
  size_t i = (size_t)row * 64 + lane;
  float v = bf2f(buf[i]);
  float t = v;
#pragma unroll
  for (int o = 32; o; o >>= 1) t += __shfl_down(t, o);
  float mean = __shfl(t, 0) * (1.f / 64.f);
  float d = v - mean;
  t = d * d;
#pragma unroll
  for (int o = 32; o; o >>= 1) t += __shfl_down(t, o);
  float var = __shfl(t, 0) * (1.f / 64.f);
  float u = d * rsqrtf(var + 1e-5f) * bf2f(s[lane]) + bf2f(b[lane]);
  buf[i] = f2bf(u / (1.f + expf(-u)));
}

// ------------------------------------------- line graph: fused edge+agg ----
// one block per node n = n0+blockIdx.x; rows [loff[n],loff[n+1]) contiguous.
// For each row p: m = mchunk[p-base]; sigma=sigmoid(m); accumulate num/den;
// if do_edge: z[p] += silu(ln(m)). Then y[n] += silu(ln(u3c[n-n0] + num/den)).
__global__ __launch_bounds__(256) void line_edgeagg_kernel(
    const bfu* __restrict__ mchunk, bfu* __restrict__ Z, bfu* __restrict__ Y,
    const bfu* __restrict__ lfused,   // u4 at +512, stride 768
    const bfu* __restrict__ u3c,
    const int* __restrict__ loff, const int* __restrict__ lsrc_p,
    int n0, int do_edge,
    const bfu* __restrict__ lns, const bfu* __restrict__ lnb,
    const bfu* __restrict__ les, const bfu* __restrict__ leb)
{
  __shared__ float sm[4];
  int n = n0 + blockIdx.x, c = threadIdx.x;
  int p0 = loff[n], p1 = loff[n + 1], base = loff[n0];
  float num = 0.f, den = 0.f;
  float esc = bf2f(les[c]), ebc = bf2f(leb[c]);
  for (int p = p0; p < p1; ++p) {
    float m = bf2f(mchunk[(size_t)(p - base) * 256 + c]);
    float sig = 1.f / (1.f + expf(-m));
    num += sig * bf2f(lfused[(size_t)lsrc_p[p] * 768 + 512 + c]);
    den += sig;
    if (do_edge) {
      float mean = block_sum256(m, sm) * (1.f / 256.f);
      float d = m - mean;
      float var = block_sum256(d * d, sm) * (1.f / 256.f);
      float u = d * rsqrtf(var + 1e-5f) * esc + ebc;
      float sil = u / (1.f + expf(-u));
      size_t zi = (size_t)p * 256 + c;
      Z[zi] = f2bf(bf2f(Z[zi]) + sil);
    }
  }
  float pre = bf2f(u3c[(size_t)(n - n0) * 256 + c]) + num / (den + 1e-6f);
  float mean = block_sum256(pre, sm) * (1.f / 256.f);
  float d = pre - mean;
  float var = block_sum256(d * d, sm) * (1.f / 256.f);
  float u = d * rsqrtf(var + 1e-5f) * bf2f(lns[c]) + bf2f(lnb[c]);
  float sil = u / (1.f + expf(-u));
  size_t yi = (size_t)n * 256 + c;
  Y[yi] = f2bf(bf2f(Y[yi]) + sil);
}

// ---------------------------------------------- atom graph: agg + update ----
__global__ __launch_bounds__(256) void agg_node_kernel(
    const bfu* __restrict__ mrows,
    const bfu* __restrict__ u4g, int u4stride,
    const bfu* __restrict__ u3g, int u3stride,
    const int* __restrict__ esrc, bfu* __restrict__ X,
    const int* __restrict__ coff, const int* __restrict__ cids,
    const bfu* __restrict__ lns, const bfu* __restrict__ lnb)
{
  __shared__ float sm[4];
  int n = blockIdx.x, c = threadIdx.x;
  int p0 = coff[n], p1 = coff[n + 1];
  float num = 0.f, den = 0.f;
  for (int p = p0; p < p1; ++p) {
    int id = cids[p];
    float sig = 1.f / (1.f + expf(-bf2f(mrows[(size_t)id * 256 + c])));
    num += sig * bf2f(u4g[(size_t)esrc[id] * u4stride + c]);
    den += sig;
  }
  float pre = bf2f(u3g[(size_t)n * u3stride + c]) + num / (den + 1e-6f);
  float mean = block_sum256(pre, sm) * (1.f / 256.f);
  float d = pre - mean;
  float var = block_sum256(d * d, sm) * (1.f / 256.f);
  float u = d * rsqrtf(var + 1e-5f) * bf2f(lns[c]) + bf2f(lnb[c]);
  float sil = u / (1.f + expf(-u));
  size_t xi = (size_t)n * 256 + c;
  X[xi] = f2bf(bf2f(X[xi]) + sil);
}

// ----------------------------------------------------------- atom init ----
__global__ __launch_bounds__(256) void atom_init_kernel(
    const bfu* __restrict__ af, const bfu* __restrict__ W, const bfu* __restrict__ bias,
    const bfu* __restrict__ lns, const bfu* __restrict__ lnb, bfu* __restrict__ X)
{
  __shared__ float sm[4];
  int row = blockIdx.x, c = threadIdx.x;
  float acc = bf2f(bias[c]);
  for (int k = 0; k < 92; ++k)
    acc += bf2f(af[row * 92 + k]) * bf2f(W[k * 256 + c]);
  float mean = block_sum256(acc, sm) * (1.f / 256.f);
  float d = acc - mean;
  float var = block_sum256(d * d, sm) * (1.f / 256.f);
  float u = d * rsqrtf(var + 1e-5f) * bf2f(lns[c]) + bf2f(lnb[c]);
  X[(size_t)row * 256 + c] = f2bf(u / (1.f + expf(-u)));
}

// --------------------------------------------------------------- final ----
__global__ __launch_bounds__(256) void final_kernel(
    const bfu* __restrict__ X, const bfu* __restrict__ fcW, const bfu* __restrict__ fcb,
    void* __restrict__ out, float* __restrict__ acc, const int* __restrict__ mode)
{
  int row = blockIdx.x * 4 + (threadIdx.x >> 6);
  int lane = threadIdx.x & 63;
  float s = 0.f;
#pragma unroll
  for (int k = 0; k < 4; ++k)
    s += bf2f(X[(size_t)row * 256 + lane + k * 64]) * bf2f(fcW[lane + k * 64]);
#pragma unroll
  for (int o = 32; o; o >>= 1) s += __shfl_down(s, o);
  if (lane == 0) {
    float v = s + bf2f(fcb[0]);
    if (*mode) ((float*)out)[1 + row] = v;
    else       ((bfu*)out)[1 + row] = f2bf(v);
    atomicAdd(acc, v);
  }
}
__global__ void mean_kernel(const float* __restrict__ acc, void* __restrict__ out,
                            const int* __restrict__ mode) {
  if (threadIdx.x == 0) {
    float v = acc[0] * (1.f / 4096.f);
    if (*mode) ((float*)out)[0] = v;
    else       ((bfu*)out)[0] = f2bf(v);
  }
}
__global__ void dbg_kernel(void* __restrict__ out, float v) {
  if (threadIdx.x == 0) { ((bfu*)out)[0] = f2bf(v); }
}

// ---------------------------------------------------------------- host ----
static void gemm128(const bfu* A, const bfu* Bt, const bfu* bias, bfu* C,
                    int M, int N, int K,
                    const int* gi0, const int* gi1, const bfu* G0, const bfu* G1, int gstride,
                    const int* coff, int cn0, int cn1, hipStream_t st) {
  if (N % 128 == 0) {
    dim3 g(M / 128, N / 128);
    gemm_kernel<128, 128, 2, 2><<<g, 256, 0, st>>>(A, Bt, bias, C, M, N, K,
        gi0, gi1, G0, G1, gstride, coff, cn0, cn1);
  } else {
    dim3 g(M / 128, N / 64);
    gemm_kernel<128, 64, 4, 1><<<g, 256, 0, st>>>(A, Bt, bias, C, M, N, K,
        gi0, gi1, G0, G1, gstride, coff, cn0, cn1);
  }
}

extern "C" void kernel_launch(void* const* d_in, const int* in_sizes, int n_in,
                              void* d_out, int out_size, void* d_ws, size_t ws_size,
                              hipStream_t stream) {
  const int N = 4096, E = 49152, T = 262144, H = 256;

  const int* src  = (const int*)d_in[2];
  const int* dst  = (const int*)d_in[3];
  const int* lsrc = (const int*)d_in[4];
  const int* ldst = (const int*)d_in[5];

  // ---- workspace carve (~265 MB, <= round-2 proven 267 MB) ----
  char* bp = (char*)d_ws;
  size_t off = 0;
  auto carve = [&](size_t bytes) -> char* {
    char* q = bp + off;
    off = (off + bytes + 255) & ~(size_t)255;
    return q;
  };
  bfu* x       = (bfu*)carve((size_t)N * H * 2);        //   2 MiB
  bfu* y       = (bfu*)carve((size_t)E * H * 2);        //  24 MiB
  bfu* z       = (bfu*)carve((size_t)T * H * 2);        // 128 MiB (ldst-sorted)
  bfu* reg     = (bfu*)carve((size_t)E * 768 * 2);      //  72 MiB
  bfu* u3c     = (bfu*)carve((size_t)CHN * H * 2);      //   2 MiB
  bfu* mchunk  = (bfu*)carve((size_t)CHCAP * H * 2);    //  12 MiB
  bfu* WtE     = (bfu*)carve((size_t)60 * H * H * 2);   // 7.5 MiB (slot-ordered)
  bfu* ebp     = (bfu*)carve((size_t)12 * 5 * H * 2);   // permuted eggc biases
  bfu* Wt_a1   = (bfu*)carve(64 * 64 * 2);
  bfu* Wt_a2   = (bfu*)carve(256 * 64 * 2);
  bfu* Wt_e1   = (bfu*)carve(64 * 96 * 2);
  bfu* Wt_e2   = (bfu*)carve(256 * 64 * 2);
  int* aoff    = (int*)carve((size_t)(N + 1) * 4);
  int* aids    = (int*)carve((size_t)E * 4);
  int* loff    = (int*)carve((size_t)(E + 1) * 4);
  int* lids    = (int*)carve((size_t)T * 4);
  int* lsrc_p  = (int*)carve((size_t)T * 4);
  int* ldst_p  = (int*)carve((size_t)T * 4);
  int* cursors = (int*)carve((size_t)E * 4);
  float* macc  = (float*)carve(256);
  int* mode    = (int*)carve(256);
  bfu* af_c    = (bfu*)carve((size_t)N * 92 * 2);
  float* r_f   = (float*)carve((size_t)E * 3 * 4);
  bfu* atW_c   = (bfu*)carve(92 * 256 * 2);
  bfu* par_c   = (bfu*)carve(8192 * 2);

  if (off > ws_size) {
    hipMemsetAsync(d_out, 0, (size_t)out_size * 2, stream);
    dbg_kernel<<<1, 64, 0, stream>>>(d_out, (float)(ws_size >> 20));
    return;
  }

  // packed small params
  bfu* atom_b_c   = par_c + 0;
  bfu* atom_lns_c = par_c + 256;
  bfu* atom_lnb_c = par_c + 512;
  bfu* e_b1_c     = par_c + 768;
  bfu* e_l1s_c    = par_c + 832;
  bfu* e_l1b_c    = par_c + 896;
  bfu* e_b2_c     = par_c + 1024;
  bfu* e_l2s_c    = par_c + 1280;
  bfu* e_l2b_c    = par_c + 1536;
  bfu* a_b1_c     = par_c + 1792;
  bfu* a_l1s_c    = par_c + 1856;
  bfu* a_l1b_c    = par_c + 1920;
  bfu* a_b2_c     = par_c + 2048;
  bfu* a_l2s_c    = par_c + 2304;
  bfu* a_l2b_c    = par_c + 2560;
  bfu* fcW_c      = par_c + 2816;
  bfu* fcb_c      = par_c + 3072;
  bfu* els_c      = (bfu*)carve((size_t)12 * 2 * H * 2);
  bfu* elb_c      = (bfu*)carve((size_t)12 * 2 * H * 2);

  // overlays within reg
  bfu* lfused = reg;                          // line: [E,768] g0|g1|u4
  bfu* afused = reg;                          // atom: [N,1024] g0|g1|u3|u4
  bfu* mbufa  = reg + (size_t)N * 1024;       // atom: [E,256]
  bfu* rbf_t  = reg;                          // early: [T,64]
  bfu* emb_t  = reg + (size_t)T * 64;         // early: [T,64]
  bfu* rbf_e  = reg;                          // early: [E,96]
  bfu* emb_e  = reg + (size_t)E * 96;         // early: [E,64]

  // ---- dtype probe + param conversion ----
  probe_kernel<<<1, 64, 0, stream>>>((const unsigned*)d_in[8], mode);
  auto cvt = [&](int idx, bfu* dstp, int n) {
    cvt_kernel<<<(n + 255) / 256, 256, 0, stream>>>(d_in[idx], dstp, n, mode);
  };
  cvt(0, af_c, N * 92);
  cvtf_kernel<<<(E * 3 + 255) / 256, 256, 0, stream>>>(d_in[1], r_f, E * 3, mode);
  cvt(6, atW_c, 92 * 256);
  cvt(7, atom_b_c, 256);  cvt(8, atom_lns_c, 256);  cvt(9, atom_lnb_c, 256);
  cvt(11, e_b1_c, 64);    cvt(12, e_l1s_c, 64);     cvt(13, e_l1b_c, 64);
  cvt(15, e_b2_c, 256);   cvt(16, e_l2s_c, 256);    cvt(17, e_l2b_c, 256);
  cvt(19, a_b1_c, 64);    cvt(20, a_l1s_c, 64);     cvt(21, a_l1b_c, 64);
  cvt(23, a_b2_c, 256);   cvt(24, a_l2s_c, 256);    cvt(25, a_l2b_c, 256);
  cvt(28, els_c, 12 * 2 * 256);
  cvt(29, elb_c, 12 * 2 * 256);
  cvt(30, fcW_c, 256);    cvt(31, fcb_c, 1);

  // ---- CSR builds + permutation indices ----
  hipMemsetAsync(cursors, 0, (size_t)N * 4, stream);
  count_kernel<<<E / 256, 256, 0, stream>>>(dst, cursors, E);
  scan_kernel<<<1, 256, 0, stream>>>(cursors, aoff, N);
  copy_kernel<<<(N + 255) / 256, 256, 0, stream>>>(aoff, cursors, N);
  fill_kernel<<<E / 256, 256, 0, stream>>>(dst, cursors, aids, E);

  hipMemsetAsync(cursors, 0, (size_t)E * 4, stream);
  count_kernel<<<T / 256, 256, 0, stream>>>(ldst, cursors, T);
  scan_kernel<<<1, 256, 0, stream>>>(cursors, loff, E);
  copy_kernel<<<(E + 255) / 256, 256, 0, stream>>>(loff, cursors, E);
  fill_kernel<<<T / 256, 256, 0, stream>>>(ldst, cursors, lids, T);
  perm_idx_kernel<<<T / 256, 256, 0, stream>>>(lids, lsrc, ldst, lsrc_p, ldst_p, T);

  // ---- weight transposes (slot-ordered for eggc) ----
  transpose_eggc_kernel<<<dim3(256, 60), 256, 0, stream>>>(d_in[26], WtE, mode);
  bias_perm_kernel<<<60, 256, 0, stream>>>(d_in[27], ebp, mode);
  transpose_pad_kernel<<<16, 256, 0, stream>>>(d_in[18], Wt_a1, 40, 64, 64, mode);
  transpose_pad_kernel<<<64, 256, 0, stream>>>(d_in[22], Wt_a2, 64, 256, 64, mode);
  transpose_pad_kernel<<<24, 256, 0, stream>>>(d_in[10], Wt_e1, 80, 64, 96, mode);
  transpose_pad_kernel<<<64, 256, 0, stream>>>(d_in[14], Wt_e2, 64, 256, 64, mode);

  // ---- z = MLP(MLP(rbf(cos))), directly in ldst-sorted order ----
  rbf_triplet_kernel<<<(T * 64) / 256, 256, 0, stream>>>(r_f, lsrc_p, ldst_p, rbf_t, T);
  gemm128(rbf_t, Wt_a1, a_b1_c, emb_t, T, 64, 64, 0, 0, 0, 0, 0, 0, 0, 0, stream);
  ln_silu64_kernel<<<T / 4, 256, 0, stream>>>(emb_t, a_l1s_c, a_l1b_c);
  gemm128(emb_t, Wt_a2, a_b2_c, z, T, 256, 64, 0, 0, 0, 0, 0, 0, 0, 0, stream);
  ln_silu256_kernel<<<T, 256, 0, stream>>>(z, z, a_l2s_c, a_l2b_c, 0);

  // ---- y = MLP(MLP(rbf(bondlength))) ----
  rbf_edge_kernel<<<(E * 96 + 255) / 256, 256, 0, stream>>>(r_f, rbf_e, E);
  gemm128(rbf_e, Wt_e1, e_b1_c, emb_e, E, 64, 96, 0, 0, 0, 0, 0, 0, 0, 0, stream);
  ln_silu64_kernel<<<E / 4, 256, 0, stream>>>(emb_e, e_l1s_c, e_l1b_c);
  gemm128(emb_e, Wt_e2, e_b2_c, y, E, 256, 64, 0, 0, 0, 0, 0, 0, 0, 0, stream);
  ln_silu256_kernel<<<E, 256, 0, stream>>>(y, y, e_l2s_c, e_l2b_c, 0);

  // ---- x = MLP(atom_features) ----
  atom_init_kernel<<<N, 256, 0, stream>>>(af_c, atW_c, atom_b_c, atom_lns_c, atom_lnb_c, x);

  // ---- EGGC blocks ----
  auto atom_eggc = [&](int blk, int do_edge) {
    const bfu* W  = WtE + (size_t)blk * 5 * H * H;
    const bfu* bb = ebp + (size_t)blk * 5 * H;
    const bfu* ls = els_c + (size_t)blk * 2 * H;
    const bfu* lb = elb_c + (size_t)blk * 2 * H;
    // batched gates: [N,1024] = x @ [W0|W1|W3|W4]
    gemm128(x, W, bb, afused, N, 1024, H, 0, 0, 0, 0, 0, 0, 0, 0, stream);
    // m = y@W2 + b2 + g0[src] + g1[dst]
    gemm128(y, W + 4 * H * H, bb + 4 * H, mbufa, E, H, H,
            src, dst, afused, afused + 256, 1024, 0, 0, 0, stream);
    agg_node_kernel<<<N, 256, 0, stream>>>(mbufa, afused + 768, 1024, afused + 512, 1024,
                                           src, x, aoff, aids, ls, lb);
    if (do_edge)
      ln_silu256_kernel<<<E, 256, 0, stream>>>(mbufa, y, ls + H, lb + H, 1);
  };

  auto line_eggc = [&](int blk, int do_edge) {
    const bfu* W  = WtE + (size_t)blk * 5 * H * H;
    const bfu* bb = ebp + (size_t)blk * 5 * H;
    const bfu* ls = els_c + (size_t)blk * 2 * H;
    const bfu* lb = elb_c + (size_t)blk * 2 * H;
    // batched gates: [E,768] = y @ [W0|W1|W4]
    gemm128(y, W, bb, lfused, E, 768, H, 0, 0, 0, 0, 0, 0, 0, 0, stream);
    for (int c = 0; c < E / CHN; ++c) {
      int n0 = c * CHN, n1 = n0 + CHN;
      // u3 for this chunk's nodes (64x64 tile -> grid 256)
      gemm_kernel<64, 64, 2, 2><<<dim3(CHN / 64, 4), 256, 0, stream>>>(
          y + (size_t)n0 * H, W + 3 * H * H, bb + 3 * H, u3c, CHN, H, H,
          0, 0, 0, 0, 0, 0, 0, 0);
      // m rows (contiguous in sorted z) + gate gathers in epilogue
      gemm_kernel<128, 128, 2, 2><<<dim3(CHCAP / 128, 2), 256, 0, stream>>>(
          z, W + 4 * H * H, bb + 4 * H, mchunk, CHCAP, H, H,
          lsrc_p, ldst_p, lfused, lfused + 256, 768, loff, n0, n1);
      line_edgeagg_kernel<<<CHN, 256, 0, stream>>>(
          mchunk, z, y, lfused, u3c, loff, lsrc_p, n0, do_edge,
          ls, lb, ls + H, lb + H);
    }
  };

  for (int i = 0; i < 4; ++i) {
    atom_eggc(2 * i, 1);
    line_eggc(2 * i + 1, i < 3);   // block 7's z-update is dead
  }
  for (int i = 0; i < 4; ++i)
    atom_eggc(8 + i, i < 3);       // block 11's y-update is dead

  // ---- output ----
  hipMemsetAsync(macc, 0, 4, stream);
  final_kernel<<<N / 4, 256, 0, stream>>>(x, fcW_c, fcb_c, d_out, macc, mode);
  mean_kernel<<<1, 64, 0, stream>>>(macc, d_out, mode);
}

// Round 5
// 3420.295 us; speedup vs baseline: 2.1878x; 1.6886x over previous
//
#include <hip/hip_runtime.h>

// ALIGNN forward on MI355X. Round 4: barrier-free wave-per-row LN/agg,
// gates moved from GEMM epilogue to coalesced consumer row-loads,
// u3-GEMM merged into m-GEMM launch, BK=64 GEMM, batched param cvt.

typedef unsigned short bfu;
typedef __attribute__((ext_vector_type(8))) short short8;   // 8 bf16
typedef __attribute__((ext_vector_type(4))) float floatx4;  // MFMA C/D

#define CHN 4096        // dst nodes per line-graph chunk (12 chunks)
#define CHCAP 24576     // row capacity per chunk (mean 21845)
#define HH 65536        // 256*256

__device__ __forceinline__ float bf2f(bfu u) {
  union { unsigned u; float f; } x; x.u = ((unsigned)u) << 16; return x.f;
}
__device__ __forceinline__ bfu f2bf(float f) {
  union { float f; unsigned u; } x; x.f = f;
  unsigned r = x.u + 0x7FFFu + ((x.u >> 16) & 1u);  // RNE
  return (bfu)(r >> 16);
}

struct f4 { float x, y, z, w; };
__device__ __forceinline__ f4 ld4(const bfu* p) {
  ushort4 u = *(const ushort4*)(const void*)p;
  return {bf2f(u.x), bf2f(u.y), bf2f(u.z), bf2f(u.w)};
}
__device__ __forceinline__ void st4(bfu* p, f4 v) {
  ushort4 u = {f2bf(v.x), f2bf(v.y), f2bf(v.z), f2bf(v.w)};
  *(ushort4*)(void*)p = u;
}
__device__ __forceinline__ f4 f4add(f4 a, f4 b) { return {a.x+b.x, a.y+b.y, a.z+b.z, a.w+b.w}; }
__device__ __forceinline__ f4 sig4(f4 m) {
  return {1.f/(1.f+expf(-m.x)), 1.f/(1.f+expf(-m.y)), 1.f/(1.f+expf(-m.z)), 1.f/(1.f+expf(-m.w))};
}
// fused mean/rstd over a 256-wide row held as 4 vals/lane across 64 lanes
__device__ __forceinline__ void wstats(f4 v, float& mean, float& rstd) {
  float s = v.x+v.y+v.z+v.w;
  float q = v.x*v.x+v.y*v.y+v.z*v.z+v.w*v.w;
#pragma unroll
  for (int m = 1; m < 64; m <<= 1) { s += __shfl_xor(s, m); q += __shfl_xor(q, m); }
  mean = s * (1.f/256.f);
  rstd = rsqrtf(fmaxf(q*(1.f/256.f) - mean*mean, 0.f) + 1e-5f);
}
// silu(ln(pre)) with gains
__device__ __forceinline__ f4 lnsilu4(f4 pre, f4 sg, f4 bb) {
  float mean, rstd; wstats(pre, mean, rstd);
  f4 u = {(pre.x-mean)*rstd*sg.x+bb.x, (pre.y-mean)*rstd*sg.y+bb.y,
          (pre.z-mean)*rstd*sg.z+bb.z, (pre.w-mean)*rstd*sg.w+bb.w};
  f4 s = sig4(u);
  return {u.x*s.x, u.y*s.y, u.z*s.z, u.w*s.w};
}

__device__ __forceinline__ float block_sum256(float t, float* sm) {
#pragma unroll
  for (int o = 32; o; o >>= 1) t += __shfl_down(t, o);
  if ((threadIdx.x & 63) == 0) sm[threadIdx.x >> 6] = t;
  __syncthreads();
  float r = sm[0] + sm[1] + sm[2] + sm[3];
  __syncthreads();
  return r;
}

// ------------------------------------------------------- dtype handling ----
__global__ void probe_kernel(const unsigned* __restrict__ ones_raw, int* __restrict__ mode) {
  if (threadIdx.x == 0) *mode = (ones_raw[0] == 0x3F800000u) ? 1 : 0;
}
__global__ __launch_bounds__(256) void cvt_kernel(
    const void* __restrict__ src, bfu* __restrict__ dst, int n, const int* __restrict__ mode) {
  int i = blockIdx.x * 256 + threadIdx.x;
  if (i >= n) return;
  dst[i] = (*mode) ? f2bf(((const float*)src)[i]) : ((const bfu*)src)[i];
}
__global__ __launch_bounds__(256) void cvtf_kernel(
    const void* __restrict__ src, float* __restrict__ dst, int n, const int* __restrict__ mode) {
  int i = blockIdx.x * 256 + threadIdx.x;
  if (i >= n) return;
  dst[i] = (*mode) ? ((const float*)src)[i] : bf2f(((const bfu*)src)[i]);
}
struct CvtDesc { const void* src; bfu* dst; int n; };
struct CvtPack { CvtDesc e[20]; };
__global__ __launch_bounds__(256) void cvt_batch_kernel(CvtPack p, const int* __restrict__ mode) {
  CvtDesc d = p.e[blockIdx.y];
  int i = blockIdx.x * 256 + threadIdx.x;
  if (i >= d.n) return;
  d.dst[i] = (*mode) ? f2bf(((const float*)d.src)[i]) : ((const bfu*)d.src)[i];
}

// ---------------------------------------------------------------- GEMM ----
// body: C[m0.., n0..] tile of A[base+row clamped to cnt][K] @ Bt[N,K] + bias
template<int BM, int BN, int WR, int WC>
__device__ __forceinline__ void gemm_body(
    const bfu* __restrict__ A, const bfu* __restrict__ Bt,
    const bfu* __restrict__ bias, bfu* __restrict__ Cout,
    int cnt, int N, int K, int base, int m0, int n0)
{
  constexpr int WM = BM / WR, WN = BN / WC;
  constexpr int TM = WM / 16, TN = WN / 16;
  constexpr int LDT = 72;  // 64 + 8 pad -> A-frag reads 2-way (free)
  static __shared__ bfu As[BM * LDT];
  static __shared__ bfu Bs[BN * LDT];

  const int tid = threadIdx.x, wave = tid >> 6, lane = tid & 63;
  const int wr = wave / WC, wc = wave % WC;
  const int lrow = lane & 15, kq = (lane >> 4) * 8;

  floatx4 acc[TM][TN];
#pragma unroll
  for (int i = 0; i < TM; ++i)
#pragma unroll
    for (int j = 0; j < TN; ++j) acc[i][j] = (floatx4){0.f, 0.f, 0.f, 0.f};

  constexpr int ACH = BM * 8, BCH = BN * 8;  // 16B chunks per tile (BK=64)
  for (int k0 = 0; k0 < K; k0 += 64) {
#pragma unroll
    for (int idx = tid; idx < ACH; idx += 256) {
      int row = idx >> 3, kc = (idx & 7) << 3;
      int r = m0 + row;
      int ar = base + (r < cnt ? r : cnt - 1);
      short8 v = *(const short8*)(const void*)(A + (size_t)ar * K + k0 + kc);
      *(short8*)(void*)(As + row * LDT + kc) = v;
    }
#pragma unroll
    for (int idx = tid; idx < BCH; idx += 256) {
      int row = idx >> 3, kc = (idx & 7) << 3;
      short8 v = *(const short8*)(const void*)(Bt + (size_t)(n0 + row) * K + k0 + kc);
      *(short8*)(void*)(Bs + row * LDT + kc) = v;
    }
    __syncthreads();
#pragma unroll
    for (int s = 0; s < 2; ++s) {
      short8 Af[TM], Bf[TN];
#pragma unroll
      for (int i = 0; i < TM; ++i)
        Af[i] = *(const short8*)(const void*)(As + (wr * WM + i * 16 + lrow) * LDT + s * 32 + kq);
#pragma unroll
      for (int j = 0; j < TN; ++j)
        Bf[j] = *(const short8*)(const void*)(Bs + (wc * WN + j * 16 + lrow) * LDT + s * 32 + kq);
#pragma unroll
      for (int i = 0; i < TM; ++i)
#pragma unroll
        for (int j = 0; j < TN; ++j)
          acc[i][j] = __builtin_amdgcn_mfma_f32_16x16x32_bf16(Af[i], Bf[j], acc[i][j], 0, 0, 0);
    }
    __syncthreads();
  }

  const int rquad = lane >> 4, cin = lane & 15;  // D: row=(lane>>4)*4+reg, col=lane&15
#pragma unroll
  for (int i = 0; i < TM; ++i) {
#pragma unroll
    for (int rr = 0; rr < 4; ++rr) {
      int orow = m0 + wr * WM + i * 16 + rquad * 4 + rr;
      if (orow >= cnt) continue;
#pragma unroll
      for (int j = 0; j < TN; ++j) {
        int gcol = n0 + wc * WN + j * 16 + cin;
        Cout[(size_t)orow * N + gcol] = f2bf(acc[i][j][rr] + bf2f(bias[gcol]));
      }
    }
  }
}

template<int BM, int BN, int WR, int WC>
__global__ __launch_bounds__(256) void gemm_kernel(
    const bfu* __restrict__ A, const bfu* __restrict__ Bt,
    const bfu* __restrict__ bias, bfu* __restrict__ Cout, int M, int N, int K)
{
  gemm_body<BM, BN, WR, WC>(A, Bt, bias, Cout, M, N, K, 0,
                            blockIdx.x * BM, blockIdx.y * BN);
}

// merged line-chunk GEMM: y<2 -> m tile (rows loff[n0..n1] of z); y==2 -> u3
__global__ __launch_bounds__(256) void line_gemm_kernel(
    const bfu* __restrict__ z, const bfu* __restrict__ yb,
    const bfu* __restrict__ W, const bfu* __restrict__ bb,
    bfu* __restrict__ mchunk, bfu* __restrict__ u3c,
    const int* __restrict__ loff, int n0, int n1)
{
  if (blockIdx.y < 2) {
    int base = loff[n0], cnt = loff[n1] - base;
    int m0 = blockIdx.x * 128;
    if (m0 >= cnt) return;
    gemm_body<128, 128, 2, 2>(z, W + 4 * HH, bb + 4 * 256, mchunk,
                              cnt, 256, 256, base, m0, blockIdx.y * 128);
  } else {
    if (blockIdx.x >= 64) return;
    gemm_body<128, 128, 2, 2>(yb + (size_t)n0 * 256, W + 3 * HH, bb + 3 * 256, u3c,
                              CHN, 256, 256, 0, (blockIdx.x & 31) * 128, (blockIdx.x >> 5) * 128);
  }
}

// ----------------------------------------------------------- CSR build ----
__global__ __launch_bounds__(256) void count_kernel(
    const int* __restrict__ d, int* __restrict__ cnt, int ne) {
  int i = blockIdx.x * 256 + threadIdx.x;
  if (i < ne) atomicAdd(&cnt[d[i]], 1);
}
__global__ __launch_bounds__(256) void scan_kernel(
    const int* __restrict__ cnt, int* __restrict__ off, int n) {
  __shared__ int ssum[256];
  __shared__ int sbase[257];
  int t = threadIdx.x;
  int strip = (n + 255) / 256;
  int lo = t * strip, hi = lo + strip; if (hi > n) hi = n; if (lo > n) lo = n;
  int s = 0;
  for (int i = lo; i < hi; ++i) s += cnt[i];
  ssum[t] = s;
  __syncthreads();
  if (t == 0) {
    int run = 0;
    for (int i = 0; i < 256; ++i) { sbase[i] = run; run += ssum[i]; }
    sbase[256] = run;
  }
  __syncthreads();
  int run = sbase[t];
  for (int i = lo; i < hi; ++i) { off[i] = run; run += cnt[i]; }
  if (t == 0) off[n] = sbase[256];
}
__global__ __launch_bounds__(256) void copy_kernel(
    const int* __restrict__ a, int* __restrict__ b, int n) {
  int i = blockIdx.x * 256 + threadIdx.x;
  if (i < n) b[i] = a[i];
}
__global__ __launch_bounds__(256) void fill_kernel(
    const int* __restrict__ d, int* __restrict__ cur, int* __restrict__ ids, int ne) {
  int i = blockIdx.x * 256 + threadIdx.x;
  if (i < ne) ids[atomicAdd(&cur[d[i]], 1)] = i;
}
__global__ __launch_bounds__(256) void perm_idx_kernel(
    const int* __restrict__ lids, const int* __restrict__ lsrc, const int* __restrict__ ldst,
    int* __restrict__ lsrc_p, int* __restrict__ ldst_p, int n) {
  int i = blockIdx.x * 256 + threadIdx.x;
  if (i >= n) return;
  int id = lids[i];
  lsrc_p[i] = lsrc[id];
  ldst_p[i] = ldst[id];
}

// ------------------------------------------------------ weight transpose ----
__global__ __launch_bounds__(256) void transpose_pad_kernel(
    const void* __restrict__ W, bfu* __restrict__ Wt, int K, int N, int Kp,
    const int* __restrict__ mode)
{
  int idx = blockIdx.x * 256 + threadIdx.x;
  if (idx >= N * Kp) return;
  int n = idx / Kp, k = idx - n * Kp;
  bfu v = 0;
  if (k < K) {
    size_t si = (size_t)k * N + n;
    v = (*mode) ? f2bf(((const float*)W)[si]) : ((const bfu*)W)[si];
  }
  Wt[idx] = v;
}
// slot order: line blocks (odd, <8): W0,W1,W4,W3,W2; atom: W0,W1,W3,W4,W2
__device__ __forceinline__ int slot2mat(int blk, int slot) {
  int is_line = (blk & 1) && (blk < 8);
  if (slot < 2) return slot;
  if (is_line) return slot == 2 ? 4 : (slot == 3 ? 3 : 2);
  return slot == 2 ? 3 : (slot == 3 ? 4 : 2);
}
__global__ __launch_bounds__(256) void transpose_eggc_kernel(
    const void* __restrict__ W, bfu* __restrict__ Wt, const int* __restrict__ mode)
{
  int bs = blockIdx.y;
  int blk = bs / 5, slot = bs - blk * 5;
  int mat = slot2mat(blk, slot);
  int idx = blockIdx.x * 256 + threadIdx.x;
  int n = idx >> 8, k = idx & 255;
  size_t si = ((size_t)(blk * 5 + mat) * 256 + k) * 256 + n;
  bfu v = (*mode) ? f2bf(((const float*)W)[si]) : ((const bfu*)W)[si];
  Wt[((size_t)bs * 256 + n) * 256 + k] = v;
}
__global__ __launch_bounds__(256) void bias_perm_kernel(
    const void* __restrict__ B, bfu* __restrict__ Bp, const int* __restrict__ mode)
{
  int i = blockIdx.x * 256 + threadIdx.x;
  int bs = i >> 8, c = i & 255;
  int blk = bs / 5, slot = bs - blk * 5;
  int mat = slot2mat(blk, slot);
  size_t si = (size_t)(blk * 5 + mat) * 256 + c;
  Bp[i] = (*mode) ? f2bf(((const float*)B)[si]) : ((const bfu*)B)[si];
}

// ----------------------------------------------------------------- RBFs ----
__global__ __launch_bounds__(256) void rbf_triplet_kernel(
    const float* __restrict__ r, const int* __restrict__ lsrc_p,
    const int* __restrict__ ldst_p, bfu* __restrict__ out, int T)
{
  int idx = blockIdx.x * 256 + threadIdx.x;
  int t = idx >> 6, j = idx & 63;
  if (t >= T) return;
  int e1 = lsrc_p[t], e2 = ldst_p[t];
  float ax = -r[e1 * 3 + 0], ay = -r[e1 * 3 + 1], az = -r[e1 * 3 + 2];
  float bx =  r[e2 * 3 + 0], by =  r[e2 * 3 + 1], bz =  r[e2 * 3 + 2];
  float dot = ax * bx + ay * by + az * bz;
  float na = sqrtf(ax * ax + ay * ay + az * az);
  float nb = sqrtf(bx * bx + by * by + bz * bz);
  float c = dot / (na * nb);
  c = fminf(1.f, fmaxf(-1.f, c));
  float v = 0.f;
  if (j < 40) {
    float center = -1.f + j * (2.f / 39.f);
    float d = c - center;
    v = expf(-19.5f * d * d);
  }
  out[(size_t)t * 64 + j] = f2bf(v);
}
__global__ __launch_bounds__(256) void rbf_edge_kernel(
    const float* __restrict__ r, bfu* __restrict__ out, int E)
{
  int idx = blockIdx.x * 256 + threadIdx.x;
  if (idx >= E * 128) return;
  int e = idx >> 7, j = idx & 127;
  float x = r[e * 3 + 0], y = r[e * 3 + 1], z = r[e * 3 + 2];
  float bl = sqrtf(x * x + y * y + z * z);
  float v = 0.f;
  if (j < 80) {
    float center = j * (8.f / 79.f);
    float d = bl - center;
    v = expf(-9.875f * d * d);
  }
  out[idx] = f2bf(v);
}

// --------------------------------------------- wave-per-row LN + SiLU ----
__global__ __launch_bounds__(256) void ln256w_kernel(
    const bfu* __restrict__ in, bfu* __restrict__ out,
    const bfu* __restrict__ s, const bfu* __restrict__ b, int residual, int rows)
{
  int row = blockIdx.x * 4 + (threadIdx.x >> 6);
  if (row >= rows) return;
  int c4 = (threadIdx.x & 63) * 4;
  f4 v = ld4(in + (size_t)row * 256 + c4);
  f4 sil = lnsilu4(v, ld4(s + c4), ld4(b + c4));
  bfu* op = out + (size_t)row * 256 + c4;
  if (residual) sil = f4add(sil, ld4(op));
  st4(op, sil);
}
__global__ __launch_bounds__(256) void ln_silu64_kernel(
    bfu* __restrict__ buf, const bfu* __restrict__ s, const bfu* __restrict__ b)
{
  int row = blockIdx.x * 4 + (threadIdx.x >> 6);
  int lane = threadIdx.x & 63;
  size_t i = (size_t)row * 64 + lane;
  float v = bf2f(buf[i]);
  float t = v;
#pragma unroll
  for (int o = 32; o; o >>= 1) t += __shfl_down(t, o);
  float mean = __shfl(t, 0) * (1.f / 64.f);
  float d = v - mean;
  t = d * d;
#pragma unroll
  for (int o = 32; o; o >>= 1) t += __shfl_down(t, o);
  float var = __shfl(t, 0) * (1.f / 64.f);
  float u = d * rsqrtf(var + 1e-5f) * bf2f(s[lane]) + bf2f(b[lane]);
  buf[i] = f2bf(u / (1.f + expf(-u)));
}

// -------------------------------------------------- atom fused edge+agg ----
// blocks [0, eblk): edge rows e -> y[e] += silu(ln(m_e)); m_e = mbuf+g0[src]+g1[dst]
// blocks [eblk, ..): node n -> x[n] += silu(ln(u3[n] + agg))
__global__ __launch_bounds__(256) void atom_fused_kernel(
    const bfu* __restrict__ mbuf, const bfu* __restrict__ af,
    const int* __restrict__ src, const int* __restrict__ dst,
    bfu* __restrict__ X, bfu* __restrict__ Y,
    const int* __restrict__ aoff, const int* __restrict__ aids,
    int eblk,
    const bfu* __restrict__ lns, const bfu* __restrict__ lnb,
    const bfu* __restrict__ les, const bfu* __restrict__ leb)
{
  int wave = threadIdx.x >> 6, c4 = (threadIdx.x & 63) * 4;
  if ((int)blockIdx.x < eblk) {
    int e = blockIdx.x * 4 + wave;
    f4 m = f4add(f4add(ld4(mbuf + (size_t)e * 256 + c4),
                       ld4(af + (size_t)src[e] * 1024 + c4)),
                 ld4(af + (size_t)dst[e] * 1024 + 256 + c4));
    f4 sil = lnsilu4(m, ld4(les + c4), ld4(leb + c4));
    bfu* op = Y + (size_t)e * 256 + c4;
    st4(op, f4add(sil, ld4(op)));
  } else {
    int n = (blockIdx.x - eblk) * 4 + wave;
    int p0 = aoff[n], p1 = aoff[n + 1];
    f4 g1 = ld4(af + (size_t)n * 1024 + 256 + c4);
    f4 num = {0, 0, 0, 0}, den = {0, 0, 0, 0};
    for (int p = p0; p < p1; ++p) {
      int id = aids[p], sx = src[id];
      f4 m = f4add(f4add(ld4(mbuf + (size_t)id * 256 + c4),
                         ld4(af + (size_t)sx * 1024 + c4)), g1);
      f4 sg = sig4(m);
      f4 u4 = ld4(af + (size_t)sx * 1024 + 768 + c4);
      num.x += sg.x * u4.x; num.y += sg.y * u4.y; num.z += sg.z * u4.z; num.w += sg.w * u4.w;
      den = f4add(den, sg);
    }
    f4 u3 = ld4(af + (size_t)n * 1024 + 512 + c4);
    f4 pre = {u3.x + num.x / (den.x + 1e-6f), u3.y + num.y / (den.y + 1e-6f),
              u3.z + num.z / (den.z + 1e-6f), u3.w + num.w / (den.w + 1e-6f)};
    f4 sil = lnsilu4(pre, ld4(lns + c4), ld4(lnb + c4));
    bfu* op = X + (size_t)n * 256 + c4;
    st4(op, f4add(sil, ld4(op)));
  }
}

// -------------------------------------------------- line fused edge+agg ----
__global__ __launch_bounds__(256) void line_fused_kernel(
    const bfu* __restrict__ mchunk, const bfu* __restrict__ lf,
    const bfu* __restrict__ u3c,
    const int* __restrict__ loff, const int* __restrict__ lsrc_p,
    const int* __restrict__ ldst_p,
    bfu* __restrict__ Z, bfu* __restrict__ Y,
    int n0, int eblk,
    const bfu* __restrict__ lns, const bfu* __restrict__ lnb,
    const bfu* __restrict__ les, const bfu* __restrict__ leb)
{
  int wave = threadIdx.x >> 6, c4 = (threadIdx.x & 63) * 4;
  int base = loff[n0];
  if ((int)blockIdx.x < eblk) {
    int rloc = blockIdx.x * 4 + wave;
    int cnt = loff[n0 + CHN] - base;
    if (rloc >= cnt) return;
    int p = base + rloc;
    f4 m = f4add(f4add(ld4(mchunk + (size_t)rloc * 256 + c4),
                       ld4(lf + (size_t)lsrc_p[p] * 768 + c4)),
                 ld4(lf + (size_t)ldst_p[p] * 768 + 256 + c4));
    f4 sil = lnsilu4(m, ld4(les + c4), ld4(leb + c4));
    bfu* op = Z + (size_t)p * 256 + c4;
    st4(op, f4add(sil, ld4(op)));
  } else {
    int n = n0 + (blockIdx.x - eblk) * 4 + wave;
    int p0 = loff[n], p1 = loff[n + 1];
    f4 g1 = ld4(lf + (size_t)n * 768 + 256 + c4);
    f4 num = {0, 0, 0, 0}, den = {0, 0, 0, 0};
    for (int p = p0; p < p1; ++p) {
      int sx = lsrc_p[p];
      f4 m = f4add(f4add(ld4(mchunk + (size_t)(p - base) * 256 + c4),
                         ld4(lf + (size_t)sx * 768 + c4)), g1);
      f4 sg = sig4(m);
      f4 u4 = ld4(lf + (size_t)sx * 768 + 512 + c4);
      num.x += sg.x * u4.x; num.y += sg.y * u4.y; num.z += sg.z * u4.z; num.w += sg.w * u4.w;
      den = f4add(den, sg);
    }
    f4 u3 = ld4(u3c + (size_t)(n - n0) * 256 + c4);
    f4 pre = {u3.x + num.x / (den.x + 1e-6f), u3.y + num.y / (den.y + 1e-6f),
              u3.z + num.z / (den.z + 1e-6f), u3.w + num.w / (den.w + 1e-6f)};
    f4 sil = lnsilu4(pre, ld4(lns + c4), ld4(lnb + c4));
    bfu* op = Y + (size_t)n * 256 + c4;
    st4(op, f4add(sil, ld4(op)));
  }
}

// ----------------------------------------------------------- atom init ----
__global__ __launch_bounds__(256) void atom_init_kernel(
    const bfu* __restrict__ af, const bfu* __restrict__ W, const bfu* __restrict__ bias,
    const bfu* __restrict__ lns, const bfu* __restrict__ lnb, bfu* __restrict__ X)
{
  __shared__ float sm[4];
  int row = blockIdx.x, c = threadIdx.x;
  float acc = bf2f(bias[c]);
  for (int k = 0; k < 92; ++k)
    acc += bf2f(af[row * 92 + k]) * bf2f(W[k * 256 + c]);
  float mean = block_sum256(acc, sm) * (1.f / 256.f);
  float d = acc - mean;
  float var = block_sum256(d * d, sm) * (1.f / 256.f);
  float u = d * rsqrtf(var + 1e-5f) * bf2f(lns[c]) + bf2f(lnb[c]);
  X[(size_t)row * 256 + c] = f2bf(u / (1.f + expf(-u)));
}

// --------------------------------------------------------------- final ----
__global__ __launch_bounds__(256) void final_kernel(
    const bfu* __restrict__ X, const bfu* __restrict__ fcW, const bfu* __restrict__ fcb,
    void* __restrict__ out, float* __restrict__ acc, const int* __restrict__ mode)
{
  int row = blockIdx.x * 4 + (threadIdx.x >> 6);
  int lane = threadIdx.x & 63;
  float s = 0.f;
#pragma unroll
  for (int k = 0; k < 4; ++k)
    s += bf2f(X[(size_t)row * 256 + lane + k * 64]) * bf2f(fcW[lane + k * 64]);
#pragma unroll
  for (int o = 32; o; o >>= 1) s += __shfl_down(s, o);
  if (lane == 0) {
    float v = s + bf2f(fcb[0]);
    if (*mode) ((float*)out)[1 + row] = v;
    else       ((bfu*)out)[1 + row] = f2bf(v);
    atomicAdd(acc, v);
  }
}
__global__ void mean_kernel(const float* __restrict__ acc, void* __restrict__ out,
                            const int* __restrict__ mode) {
  if (threadIdx.x == 0) {
    float v = acc[0] * (1.f / 4096.f);
    if (*mode) ((float*)out)[0] = v;
    else       ((bfu*)out)[0] = f2bf(v);
  }
}
__global__ void dbg_kernel(void* __restrict__ out, float v) {
  if (threadIdx.x == 0) { ((bfu*)out)[0] = f2bf(v); }
}

// ---------------------------------------------------------------- host ----
static void gemm128(const bfu* A, const bfu* Bt, const bfu* bias, bfu* C,
                    int M, int N, int K, hipStream_t st) {
  if (N % 128 == 0) {
    dim3 g(M / 128, N / 128);
    gemm_kernel<128, 128, 2, 2><<<g, 256, 0, st>>>(A, Bt, bias, C, M, N, K);
  } else {
    dim3 g(M / 128, N / 64);
    gemm_kernel<128, 64, 4, 1><<<g, 256, 0, st>>>(A, Bt, bias, C, M, N, K);
  }
}

extern "C" void kernel_launch(void* const* d_in, const int* in_sizes, int n_in,
                              void* d_out, int out_size, void* d_ws, size_t ws_size,
                              hipStream_t stream) {
  const int N = 4096, E = 49152, T = 262144, H = 256;

  const int* src  = (const int*)d_in[2];
  const int* dst  = (const int*)d_in[3];
  const int* lsrc = (const int*)d_in[4];
  const int* ldst = (const int*)d_in[5];

  // ---- workspace carve (~265 MB, proven fit) ----
  char* bp = (char*)d_ws;
  size_t off = 0;
  auto carve = [&](size_t bytes) -> char* {
    char* q = bp + off;
    off = (off + bytes + 255) & ~(size_t)255;
    return q;
  };
  bfu* x       = (bfu*)carve((size_t)N * H * 2);
  bfu* y       = (bfu*)carve((size_t)E * H * 2);
  bfu* z       = (bfu*)carve((size_t)T * H * 2);       // ldst-sorted
  bfu* reg     = (bfu*)carve((size_t)E * 768 * 2);
  bfu* u3c     = (bfu*)carve((size_t)CHN * H * 2);
  bfu* mchunk  = (bfu*)carve((size_t)CHCAP * H * 2);
  bfu* WtE     = (bfu*)carve((size_t)60 * H * H * 2);  // slot-ordered
  bfu* ebp     = (bfu*)carve((size_t)12 * 5 * H * 2);
  bfu* Wt_a1   = (bfu*)carve(64 * 64 * 2);
  bfu* Wt_a2   = (bfu*)carve(256 * 64 * 2);
  bfu* Wt_e1   = (bfu*)carve(64 * 128 * 2);
  bfu* Wt_e2   = (bfu*)carve(256 * 64 * 2);
  int* aoff    = (int*)carve((size_t)(N + 1) * 4);
  int* aids    = (int*)carve((size_t)E * 4);
  int* loff    = (int*)carve((size_t)(E + 1) * 4);
  int* lids    = (int*)carve((size_t)T * 4);
  int* lsrc_p  = (int*)carve((size_t)T * 4);
  int* ldst_p  = (int*)carve((size_t)T * 4);
  int* cursors = (int*)carve((size_t)E * 4);
  float* macc  = (float*)carve(256);
  int* mode    = (int*)carve(256);
  bfu* af_c    = (bfu*)carve((size_t)N * 92 * 2);
  float* r_f   = (float*)carve((size_t)E * 3 * 4);
  bfu* atW_c   = (bfu*)carve(92 * 256 * 2);
  bfu* par_c   = (bfu*)carve(8192 * 2);
  bfu* els_c   = (bfu*)carve((size_t)12 * 2 * H * 2);
  bfu* elb_c   = (bfu*)carve((size_t)12 * 2 * H * 2);

  if (off > ws_size) {
    hipMemsetAsync(d_out, 0, (size_t)out_size * 2, stream);
    dbg_kernel<<<1, 64, 0, stream>>>(d_out, (float)(ws_size >> 20));
    return;
  }

  // packed small params
  bfu* atom_b_c   = par_c + 0;
  bfu* atom_lns_c = par_c + 256;
  bfu* atom_lnb_c = par_c + 512;
  bfu* e_b1_c     = par_c + 768;
  bfu* e_l1s_c    = par_c + 832;
  bfu* e_l1b_c    = par_c + 896;
  bfu* e_b2_c     = par_c + 1024;
  bfu* e_l2s_c    = par_c + 1280;
  bfu* e_l2b_c    = par_c + 1536;
  bfu* a_b1_c     = par_c + 1792;
  bfu* a_l1s_c    = par_c + 1856;
  bfu* a_l1b_c    = par_c + 1920;
  bfu* a_b2_c     = par_c + 2048;
  bfu* a_l2s_c    = par_c + 2304;
  bfu* a_l2b_c    = par_c + 2560;
  bfu* fcW_c      = par_c + 2816;
  bfu* fcb_c      = par_c + 3072;

  // overlays within reg
  bfu* lfused = reg;                        // line: [E,768] g0|g1|u4
  bfu* afused = reg;                        // atom: [N,1024] g0|g1|u3|u4
  bfu* mbufa  = reg + (size_t)N * 1024;     // atom: [E,256]
  bfu* rbf_t  = reg;                        // early: [T,64]
  bfu* emb_t  = reg + (size_t)T * 64;       // early: [T,64]
  bfu* rbf_e  = reg;                        // early: [E,128]
  bfu* emb_e  = reg + (size_t)E * 128;      // early: [E,64]

  // ---- dtype probe + param conversion (batched) ----
  probe_kernel<<<1, 64, 0, stream>>>((const unsigned*)d_in[8], mode);
  CvtPack pk;
  int ii = 0;
  auto add = [&](int idx, bfu* dstp, int n) { pk.e[ii++] = {d_in[idx], dstp, n}; };
  add(7, atom_b_c, 256);  add(8, atom_lns_c, 256); add(9, atom_lnb_c, 256);
  add(11, e_b1_c, 64);    add(12, e_l1s_c, 64);    add(13, e_l1b_c, 64);
  add(15, e_b2_c, 256);   add(16, e_l2s_c, 256);   add(17, e_l2b_c, 256);
  add(19, a_b1_c, 64);    add(20, a_l1s_c, 64);    add(21, a_l1b_c, 64);
  add(23, a_b2_c, 256);   add(24, a_l2s_c, 256);   add(25, a_l2b_c, 256);
  add(30, fcW_c, 256);    add(31, fcb_c, 1);
  add(28, els_c, 12 * 2 * 256);
  add(29, elb_c, 12 * 2 * 256);
  add(6, atW_c, 92 * 256);
  cvt_batch_kernel<<<dim3(92, 20), 256, 0, stream>>>(pk, mode);
  cvt_kernel<<<(N * 92 + 255) / 256, 256, 0, stream>>>(d_in[0], af_c, N * 92, mode);
  cvtf_kernel<<<(E * 3 + 255) / 256, 256, 0, stream>>>(d_in[1], r_f, E * 3, mode);

  // ---- CSR builds + permutation indices ----
  hipMemsetAsync(cursors, 0, (size_t)N * 4, stream);
  count_kernel<<<E / 256, 256, 0, stream>>>(dst, cursors, E);
  scan_kernel<<<1, 256, 0, stream>>>(cursors, aoff, N);
  copy_kernel<<<(N + 255) / 256, 256, 0, stream>>>(aoff, cursors, N);
  fill_kernel<<<E / 256, 256, 0, stream>>>(dst, cursors, aids, E);

  hipMemsetAsync(cursors, 0, (size_t)E * 4, stream);
  count_kernel<<<T / 256, 256, 0, stream>>>(ldst, cursors, T);
  scan_kernel<<<1, 256, 0, stream>>>(cursors, loff, E);
  copy_kernel<<<(E + 255) / 256, 256, 0, stream>>>(loff, cursors, E);
  fill_kernel<<<T / 256, 256, 0, stream>>>(ldst, cursors, lids, T);
  perm_idx_kernel<<<T / 256, 256, 0, stream>>>(lids, lsrc, ldst, lsrc_p, ldst_p, T);

  // ---- weight transposes ----
  transpose_eggc_kernel<<<dim3(256, 60), 256, 0, stream>>>(d_in[26], WtE, mode);
  bias_perm_kernel<<<60, 256, 0, stream>>>(d_in[27], ebp, mode);
  transpose_pad_kernel<<<16, 256, 0, stream>>>(d_in[18], Wt_a1, 40, 64, 64, mode);
  transpose_pad_kernel<<<64, 256, 0, stream>>>(d_in[22], Wt_a2, 64, 256, 64, mode);
  transpose_pad_kernel<<<32, 256, 0, stream>>>(d_in[10], Wt_e1, 80, 64, 128, mode);
  transpose_pad_kernel<<<64, 256, 0, stream>>>(d_in[14], Wt_e2, 64, 256, 64, mode);

  // ---- z = MLP(MLP(rbf(cos))), in ldst-sorted order ----
  rbf_triplet_kernel<<<(T * 64) / 256, 256, 0, stream>>>(r_f, lsrc_p, ldst_p, rbf_t, T);
  gemm128(rbf_t, Wt_a1, a_b1_c, emb_t, T, 64, 64, stream);
  ln_silu64_kernel<<<T / 4, 256, 0, stream>>>(emb_t, a_l1s_c, a_l1b_c);
  gemm128(emb_t, Wt_a2, a_b2_c, z, T, 256, 64, stream);
  ln256w_kernel<<<T / 4, 256, 0, stream>>>(z, z, a_l2s_c, a_l2b_c, 0, T);

  // ---- y = MLP(MLP(rbf(bondlength))) ----
  rbf_edge_kernel<<<(E * 128) / 256, 256, 0, stream>>>(r_f, rbf_e, E);
  gemm128(rbf_e, Wt_e1, e_b1_c, emb_e, E, 64, 128, stream);
  ln_silu64_kernel<<<E / 4, 256, 0, stream>>>(emb_e, e_l1s_c, e_l1b_c);
  gemm128(emb_e, Wt_e2, e_b2_c, y, E, 256, 64, stream);
  ln256w_kernel<<<E / 4, 256, 0, stream>>>(y, y, e_l2s_c, e_l2b_c, 0, E);

  // ---- x = MLP(atom_features) ----
  atom_init_kernel<<<N, 256, 0, stream>>>(af_c, atW_c, atom_b_c, atom_lns_c, atom_lnb_c, x);

  // ---- EGGC blocks ----
  auto atom_eggc = [&](int blk, int do_edge) {
    const bfu* W  = WtE + (size_t)blk * 5 * HH;
    const bfu* bb = ebp + (size_t)blk * 5 * H;
    const bfu* ls = els_c + (size_t)blk * 2 * H;
    const bfu* lb = elb_c + (size_t)blk * 2 * H;
    gemm128(x, W, bb, afused, N, 1024, H, stream);           // gates g0|g1|u3|u4
    gemm128(y, W + 4 * HH, bb + 4 * H, mbufa, E, H, H, stream);  // m_raw
    int eblk = do_edge ? E / 4 : 0;
    atom_fused_kernel<<<eblk + N / 4, 256, 0, stream>>>(
        mbufa, afused, src, dst, x, y, aoff, aids, eblk, ls, lb, ls + H, lb + H);
  };

  auto line_eggc = [&](int blk, int do_edge) {
    const bfu* W  = WtE + (size_t)blk * 5 * HH;
    const bfu* bb = ebp + (size_t)blk * 5 * H;
    const bfu* ls = els_c + (size_t)blk * 2 * H;
    const bfu* lb = elb_c + (size_t)blk * 2 * H;
    gemm128(y, W, bb, lfused, E, 768, H, stream);            // gates g0|g1|u4
    for (int c = 0; c < E / CHN; ++c) {
      int n0 = c * CHN;
      line_gemm_kernel<<<dim3(CHCAP / 128, 3), 256, 0, stream>>>(
          z, y, W, bb, mchunk, u3c, loff, n0, n0 + CHN);
      int eblk = do_edge ? CHCAP / 4 : 0;
      line_fused_kernel<<<eblk + CHN / 4, 256, 0, stream>>>(
          mchunk, lfused, u3c, loff, lsrc_p, ldst_p, z, y, n0, eblk,
          ls, lb, ls + H, lb + H);
    }
  };

  for (int i = 0; i < 4; ++i) {
    atom_eggc(2 * i, 1);
    line_eggc(2 * i + 1, i < 3);   // block 7's z-update is dead
  }
  for (int i = 0; i < 4; ++i)
    atom_eggc(8 + i, i < 3);       // block 11's y-update is dead

  // ---- output ----
  hipMemsetAsync(macc, 0, 4, stream);
  final_kernel<<<N / 4, 256, 0, stream>>>(x, fcW_c, fcb_c, d_out, macc, mode);
  mean_kernel<<<1, 64, 0, stream>>>(macc, d_out, mode);
}